// Round 2
// baseline (3456.543 us; speedup 1.0000x reference)
//
#include <hip/hip_runtime.h>
#include <cstdint>
#include <cstddef>

// Problem constants
#define N_NODE_C 20000
#define N_EDGE_C 40000
#define DD 128
#define BN_EPS_F 1e-5f
#define NSB 160           // cov partial blocks (40000/160 = 250 rows each)

// ---------------------------------------------------------------------------
// K0: transpose W_ih / W_hh (384x128 -> 128x384) so GRU GEMMs read B coalesced
__global__ __launch_bounds__(256) void k_transpose_gru(
    const float* __restrict__ Wih, const float* __restrict__ Whh,
    float* __restrict__ WihT, float* __restrict__ WhhT) {
  int i = blockIdx.x * 256 + threadIdx.x;           // 0..98303
  int which = i / 49152;
  int idx = i - which * 49152;                      // k*384+o
  int k = idx / 384, o = idx - k * 384;
  float v = which ? Whh[o * 128 + k] : Wih[o * 128 + k];
  if (which) WhhT[idx] = v; else WihT[idx] = v;
}

// ---------------------------------------------------------------------------
// K1: y1 = edge(40000x16) @ W1(16x256)
__global__ __launch_bounds__(256) void k_edge_w1(
    const float* __restrict__ edge, const float* __restrict__ W1,
    float* __restrict__ y1) {
  __shared__ float el[16][16];
  int e0 = blockIdx.x * 16;
  int t = threadIdx.x;
  el[t >> 4][t & 15] = edge[(size_t)e0 * 16 + t];
  __syncthreads();
  float w[16];
#pragma unroll
  for (int k = 0; k < 16; ++k) w[k] = W1[k * 256 + t];
#pragma unroll 4
  for (int e = 0; e < 16; ++e) {
    float acc = 0.f;
#pragma unroll
    for (int k = 0; k < 16; ++k) acc = fmaf(el[e][k], w[k], acc);
    y1[(size_t)(e0 + e) * 256 + t] = acc;
  }
}

// ---------------------------------------------------------------------------
// K2: per-column sum / sumsq (f64 atomics) of y[E x J], J in {128,256}
__global__ __launch_bounds__(256) void k_colstats(
    const float* __restrict__ y, int E, int J,
    double* __restrict__ sum, double* __restrict__ sumsq) {
  int t = threadIdx.x;
  int rpi = 256 / J;
  int col = t & (J - 1);
  int rof = t / J;
  double s = 0.0, q = 0.0;
  for (int r = blockIdx.x * rpi + rof; r < E; r += gridDim.x * rpi) {
    float v = y[(size_t)r * J + col];
    s += v;
    q += (double)v * (double)v;
  }
  atomicAdd(&sum[col], s);
  atomicAdd(&sumsq[col], q);
}

// K3: finalize BN affine per column: a = g*rsqrt(var+eps), b = be - mu*a
__global__ void k_finalize(const double* __restrict__ sum,
                           const double* __restrict__ sumsq,
                           const float* __restrict__ g,
                           const float* __restrict__ be,
                           float* __restrict__ a, float* __restrict__ b,
                           int J, double invE) {
  int j = threadIdx.x;
  if (j < J) {
    double mu = sum[j] * invE;
    double var = sumsq[j] * invE - mu * mu;
    float rstd = (float)(1.0 / sqrt(var + 1e-5));
    float aa = g[j] * rstd;
    a[j] = aa;
    b[j] = be[j] - (float)mu * aa;
  }
}

// ---------------------------------------------------------------------------
// K4: C[M,N] = T(A[M,K]) @ B[K,N] (+bias). MODE 1: T = relu(a*x+b) per A-col.
// BM=64, BN=128 (grid.y tiles N), BK=32, 256 thr, 8x4 per thread.
template <int MODE>
__global__ __launch_bounds__(256) void k_gemm(
    const float* __restrict__ A, const float* __restrict__ B,
    float* __restrict__ C, int M, int K, int N,
    const float* __restrict__ ta, const float* __restrict__ tb,
    const float* __restrict__ bias) {
  __shared__ float At[32][64];
  __shared__ float Bt[32][128];
  int mb = blockIdx.x * 64, nb = blockIdx.y * 128;
  int tid = threadIdx.x;
  int tr = tid >> 5, tc = tid & 31;
  float acc[8][4];
#pragma unroll
  for (int i = 0; i < 8; ++i)
#pragma unroll
    for (int j = 0; j < 4; ++j) acc[i][j] = 0.f;
  int arow = tid >> 2, akc = (tid & 3) * 8;
  int bkr = tid >> 3, bcol = (tid & 7) * 16;
  for (int k0 = 0; k0 < K; k0 += 32) {
    {  // stage A (transposed, transform applied)
      int gr = mb + arow;
      float vv[8];
      if (gr < M) {
        float4 v0 = *(const float4*)&A[(size_t)gr * K + k0 + akc];
        float4 v1 = *(const float4*)&A[(size_t)gr * K + k0 + akc + 4];
        vv[0] = v0.x; vv[1] = v0.y; vv[2] = v0.z; vv[3] = v0.w;
        vv[4] = v1.x; vv[5] = v1.y; vv[6] = v1.z; vv[7] = v1.w;
      } else {
#pragma unroll
        for (int u = 0; u < 8; ++u) vv[u] = 0.f;
      }
#pragma unroll
      for (int u = 0; u < 8; ++u) {
        float x = vv[u];
        if (MODE == 1) {
          int k = k0 + akc + u;
          x = fmaxf(fmaf(x, ta[k], tb[k]), 0.f);
        }
        At[akc + u][arow] = x;
      }
    }
    {  // stage B
      const float* src = &B[(size_t)(k0 + bkr) * N + nb + bcol];
      float4* d = (float4*)&Bt[bkr][bcol];
      d[0] = ((const float4*)src)[0];
      d[1] = ((const float4*)src)[1];
      d[2] = ((const float4*)src)[2];
      d[3] = ((const float4*)src)[3];
    }
    __syncthreads();
#pragma unroll 8
    for (int kk = 0; kk < 32; ++kk) {
      float4 a0 = *(float4*)&At[kk][tr * 8];
      float4 a1 = *(float4*)&At[kk][tr * 8 + 4];
      float4 b0 = *(float4*)&Bt[kk][tc * 4];
      float av[8] = {a0.x, a0.y, a0.z, a0.w, a1.x, a1.y, a1.z, a1.w};
      float bv[4] = {b0.x, b0.y, b0.z, b0.w};
#pragma unroll
      for (int i = 0; i < 8; ++i)
#pragma unroll
        for (int j = 0; j < 4; ++j)
          acc[i][j] = fmaf(av[i], bv[j], acc[i][j]);
    }
    __syncthreads();
  }
#pragma unroll
  for (int i = 0; i < 8; ++i) {
    int gr = mb + tr * 8 + i;
    if (gr < M) {
      int oc = nb + tc * 4;
      float4 o;
      o.x = acc[i][0]; o.y = acc[i][1]; o.z = acc[i][2]; o.w = acc[i][3];
      if (bias) {
        o.x += bias[oc]; o.y += bias[oc + 1];
        o.z += bias[oc + 2]; o.w += bias[oc + 3];
      }
      *(float4*)&C[(size_t)gr * N + oc] = o;
    }
  }
}

// ---------------------------------------------------------------------------
// K5: in-place h = relu(a*y + b) per column (J=128)
__global__ __launch_bounds__(256) void k_bnrelu_inplace(
    float* __restrict__ y, const float* __restrict__ a,
    const float* __restrict__ b, int n, int J) {
  int i = blockIdx.x * 256 + threadIdx.x;
  if (i < n) {
    int c = i & (J - 1);
    y[i] = fmaxf(fmaf(y[i], a[c], b[c]), 0.f);
  }
}

// ---------------------------------------------------------------------------
// K6: per-block partials of h3^T h3 (128x128) and column sums (for Cov trick)
__global__ __launch_bounds__(256) void k_cov_partials(
    const float* __restrict__ h3, float* __restrict__ Spart,
    float* __restrict__ hbarP) {
  __shared__ float hl[2][128];
  int b = blockIdx.x;  // NSB blocks, 250 rows each
  int t = threadIdx.x;
  int tr = t >> 4, tc = t & 15;  // 16x16 threads, each 8x8 outputs
  float acc[8][8];
#pragma unroll
  for (int i = 0; i < 8; ++i)
#pragma unroll
    for (int j = 0; j < 8; ++j) acc[i][j] = 0.f;
  float cs = 0.f;
  int r0 = b * 250;
  for (int rs = 0; rs < 250; rs += 2) {
    hl[t >> 7][t & 127] = h3[(size_t)(r0 + rs + (t >> 7)) * 128 + (t & 127)];
    __syncthreads();
#pragma unroll
    for (int rr = 0; rr < 2; ++rr) {
      float a0[8], b0[8];
#pragma unroll
      for (int i = 0; i < 8; ++i) a0[i] = hl[rr][tr * 8 + i];
#pragma unroll
      for (int j = 0; j < 8; ++j) b0[j] = hl[rr][tc * 8 + j];
#pragma unroll
      for (int i = 0; i < 8; ++i)
#pragma unroll
        for (int j = 0; j < 8; ++j)
          acc[i][j] = fmaf(a0[i], b0[j], acc[i][j]);
    }
    if (t < 128) cs += hl[0][t] + hl[1][t];
    __syncthreads();
  }
  float* sp = &Spart[(size_t)b * 16384];
#pragma unroll
  for (int i = 0; i < 8; ++i)
#pragma unroll
    for (int j = 0; j < 8; j += 4) {
      float4 o;
      o.x = acc[i][j]; o.y = acc[i][j + 1];
      o.z = acc[i][j + 2]; o.w = acc[i][j + 3];
      *(float4*)&sp[(tr * 8 + i) * 128 + tc * 8 + j] = o;
    }
  if (t < 128) hbarP[b * 128 + t] = cs;
}

// K7a: hbar = (sum of partial colsums)/E  (f64)
__global__ void k_hbar(const float* __restrict__ hbarP,
                       double* __restrict__ hbarD, float* __restrict__ hbarF) {
  int t = threadIdx.x;  // 128
  double s = 0.0;
  for (int b = 0; b < NSB; ++b) s += (double)hbarP[b * 128 + t];
  s *= (1.0 / 40000.0);
  hbarD[t] = s;
  hbarF[t] = (float)s;
}

// K7b: Cov[k,l] = S/E - hbar_k*hbar_l  (f64 combine, f32 out)
__global__ __launch_bounds__(256) void k_cov(
    const float* __restrict__ Spart, const double* __restrict__ hbarD,
    float* __restrict__ Cov) {
  int i = blockIdx.x * 256 + threadIdx.x;  // < 16384
  int k = i >> 7, l = i & 127;
  double s = 0.0;
  for (int b = 0; b < NSB; ++b) s += (double)Spart[(size_t)b * 16384 + i];
  Cov[i] = (float)(s * (1.0 / 40000.0) - hbarD[k] * hbarD[l]);
}

// K8a: U = Cov @ W4  (128 x 16384), 128 blocks: (16 k-tiles x 8 j-tiles)
__global__ __launch_bounds__(256) void k_covW4(
    const float* __restrict__ Cov, const float* __restrict__ W4,
    float* __restrict__ U) {
  __shared__ float cl[8][128];
  int bk = blockIdx.x & 15, bj = blockIdx.x >> 4;
  int k0 = bk * 8, j0 = bj * 2048;
  int t = threadIdx.x;
  {
    float4 v = *(const float4*)&Cov[(size_t)(k0 + (t >> 5)) * 128 + (t & 31) * 4];
    *(float4*)&cl[t >> 5][(t & 31) * 4] = v;
  }
  __syncthreads();
  for (int ji = 0; ji < 8; ++ji) {
    int j = j0 + ji * 256 + t;
    float acc[8];
#pragma unroll
    for (int i = 0; i < 8; ++i) acc[i] = 0.f;
#pragma unroll 4
    for (int l = 0; l < 128; ++l) {
      float w = W4[(size_t)l * 16384 + j];
#pragma unroll
      for (int i = 0; i < 8; ++i) acc[i] = fmaf(cl[i][l], w, acc[i]);
    }
#pragma unroll
    for (int i = 0; i < 8; ++i) U[(size_t)(k0 + i) * 16384 + j] = acc[i];
  }
}

// K8b: mu4[j] = hbar.W4[:,j]; var4[j] = W4[:,j].U[:,j]; -> a4, nb4
__global__ __launch_bounds__(256) void k_a4nb4(
    const float* __restrict__ W4, const float* __restrict__ U,
    const float* __restrict__ hbarF, const float* __restrict__ g4,
    const float* __restrict__ be4, float* __restrict__ a4,
    float* __restrict__ nb4) {
  __shared__ float hb[128];
  int t = threadIdx.x;
  if (t < 128) hb[t] = hbarF[t];
  __syncthreads();
  int j = blockIdx.x * 256 + t;  // 64 blocks -> 16384
  float macc = 0.f, vacc = 0.f;
#pragma unroll 4
  for (int k = 0; k < 128; ++k) {
    float w = W4[(size_t)k * 16384 + j];
    macc = fmaf(hb[k], w, macc);
    vacc = fmaf(w, U[(size_t)k * 16384 + j], vacc);
  }
  float aa = g4[j] * (1.0f / sqrtf(vacc + BN_EPS_F));
  a4[j] = aa;
  nb4[j] = be4[j] - macc * aa;
}

// K9: Bbig[i<2097152] = W4[i]*a4[i&16383];  tail 16384 rowsx128 = nb4
__global__ __launch_bounds__(256) void k_buildB(
    const float* __restrict__ W4, const float* __restrict__ a4,
    const float* __restrict__ nb4, float* __restrict__ Bbig) {
  size_t i = (size_t)blockIdx.x * 256 + threadIdx.x;  // exact 2,113,536
  if (i < 2097152)
    Bbig[i] = W4[i] * a4[i & 16383];
  else
    Bbig[i] = nb4[i - 2097152];
}

// ---------------------------------------------------------------------------
// K10: fused big GEMM. message[e,f] = sum_kk P[e,kk]*Bbig[kk,f], K=16512,
// P generated on the fly (outer product h3 x gathered node row; tail = x).
// Epilogue scatters atomically into msum (segment sum) + cnt.
// BM=32, BN=128, BK=32, 256 thr, 4x4 per thread.
__global__ __launch_bounds__(256) void k_biggemm(
    const float* __restrict__ h3, const float* __restrict__ node,
    const int* __restrict__ eidx, const float* __restrict__ Bbig,
    float* __restrict__ msum, float* __restrict__ cnt) {
  __shared__ float xl[32][128];
  __shared__ float hl[32][128];
  __shared__ float At[32][36];  // padded: gen-writes spread banks (9t mod 32)
  __shared__ float Bt[32][128];
  __shared__ int sidx[32], didx[32];
  int e0 = blockIdx.x * 32;
  int t = threadIdx.x;
  if (t < 64) {
    int e = t >> 1;
    int v = eidx[(size_t)(e0 + e) * 2 + (t & 1)];
    if (t & 1) didx[e] = v; else sidx[e] = v;
  }
  __syncthreads();
  {
    int row = t >> 3, c = (t & 7) * 16;
    const float* xs = &node[(size_t)sidx[row] * 128 + c];
    const float* hs = &h3[(size_t)(e0 + row) * 128 + c];
#pragma unroll
    for (int v = 0; v < 4; ++v) {
      ((float4*)&xl[row][c])[v] = ((const float4*)xs)[v];
      ((float4*)&hl[row][c])[v] = ((const float4*)hs)[v];
    }
  }
  float acc[4][4];
#pragma unroll
  for (int i = 0; i < 4; ++i)
#pragma unroll
    for (int j = 0; j < 4; ++j) acc[i][j] = 0.f;
  int tr = t >> 5, tc = t & 31;
  int gkk = t & 31, geb = (t >> 5) * 4;  // A-gen mapping (lanes vary kk)
  int bkr = t >> 3, bc = (t & 7) * 16;
  __syncthreads();
  for (int kt = 0; kt < 16512; kt += 32) {
    {  // generate A tile from outer product (+ bias tail)
      int kk = kt + gkk;
      float4 av;
      if (kk < 16384) {
        int k = kk >> 7, dd = kk & 127;
        av.x = hl[geb + 0][k] * xl[geb + 0][dd];
        av.y = hl[geb + 1][k] * xl[geb + 1][dd];
        av.z = hl[geb + 2][k] * xl[geb + 2][dd];
        av.w = hl[geb + 3][k] * xl[geb + 3][dd];
      } else {
        int dd = kk - 16384;
        av.x = xl[geb + 0][dd]; av.y = xl[geb + 1][dd];
        av.z = xl[geb + 2][dd]; av.w = xl[geb + 3][dd];
      }
      *(float4*)&At[gkk][geb] = av;
    }
    {  // stage B tile
      const float* bs = &Bbig[(size_t)(kt + bkr) * 128 + bc];
      float4* dp = (float4*)&Bt[bkr][bc];
#pragma unroll
      for (int v = 0; v < 4; ++v) dp[v] = ((const float4*)bs)[v];
    }
    __syncthreads();
#pragma unroll 8
    for (int kk = 0; kk < 32; ++kk) {
      float4 a = *(float4*)&At[kk][tr * 4];
      float4 b = *(float4*)&Bt[kk][tc * 4];
      float av[4] = {a.x, a.y, a.z, a.w};
      float bv[4] = {b.x, b.y, b.z, b.w};
#pragma unroll
      for (int i = 0; i < 4; ++i)
#pragma unroll
        for (int j = 0; j < 4; ++j)
          acc[i][j] = fmaf(av[i], bv[j], acc[i][j]);
    }
    __syncthreads();
  }
#pragma unroll
  for (int i = 0; i < 4; ++i) {
    int n = didx[tr * 4 + i];
    float* dstp = &msum[(size_t)n * 128 + tc * 4];
    atomicAdd(dstp + 0, acc[i][0]);
    atomicAdd(dstp + 1, acc[i][1]);
    atomicAdd(dstp + 2, acc[i][2]);
    atomicAdd(dstp + 3, acc[i][3]);
  }
  if (tc == 0) {
#pragma unroll
    for (int i = 0; i < 4; ++i) atomicAdd(&cnt[didx[tr * 4 + i]], 1.0f);
  }
}

// ---------------------------------------------------------------------------
// K11: msg = relu(msum/max(cnt,1) + bias)
__global__ __launch_bounds__(256) void k_msg(
    const float* __restrict__ msum, const float* __restrict__ cnt,
    const float* __restrict__ bias, float* __restrict__ msg) {
  int i = blockIdx.x * 256 + threadIdx.x;  // exact 2,560,000
  int nn = i >> 7, f = i & 127;
  float m = msum[i] / fmaxf(cnt[nn], 1.0f);
  msg[i] = fmaxf(m + bias[f], 0.f);
}

// K12: GRU gates -> h1, written twice (tuple output h1, h1[None])
__global__ __launch_bounds__(256) void k_gru(
    const float* __restrict__ gi, const float* __restrict__ gh,
    const float* __restrict__ h0, float* __restrict__ out) {
  int i = blockIdx.x * 256 + threadIdx.x;  // exact 2,560,000
  int nn = i >> 7, f = i & 127;
  size_t base = (size_t)nn * 384;
  float ir = gi[base + f], hr = gh[base + f];
  float iz = gi[base + 128 + f], hz = gh[base + 128 + f];
  float in_ = gi[base + 256 + f], hn = gh[base + 256 + f];
  float r = 1.f / (1.f + expf(-(ir + hr)));
  float z = 1.f / (1.f + expf(-(iz + hz)));
  float n = tanhf(in_ + r * hn);
  float h1 = (1.f - z) * n + z * h0[i];
  out[i] = h1;
  out[2560000 + i] = h1;
}

// ---------------------------------------------------------------------------
extern "C" void kernel_launch(void* const* d_in, const int* in_sizes, int n_in,
                              void* d_out, int out_size, void* d_ws,
                              size_t ws_size, hipStream_t stream) {
  (void)in_sizes; (void)n_in; (void)out_size; (void)ws_size;
  const float* node = (const float*)d_in[0];
  const int* eidx = (const int*)d_in[1];
  const float* edge = (const float*)d_in[2];
  const float* hidden = (const float*)d_in[3];
  const float* W1 = (const float*)d_in[4];
  const float* g1 = (const float*)d_in[5];
  const float* be1 = (const float*)d_in[6];
  const float* W2 = (const float*)d_in[7];
  const float* g2 = (const float*)d_in[8];
  const float* be2 = (const float*)d_in[9];
  const float* W3 = (const float*)d_in[10];
  const float* g3 = (const float*)d_in[11];
  const float* be3 = (const float*)d_in[12];
  const float* W4 = (const float*)d_in[13];
  const float* g4 = (const float*)d_in[14];
  const float* be4 = (const float*)d_in[15];
  const float* bias = (const float*)d_in[16];
  const float* Wih = (const float*)d_in[17];
  const float* Whh = (const float*)d_in[18];
  const float* bih = (const float*)d_in[19];
  const float* bhh = (const float*)d_in[20];
  float* out = (float*)d_out;

  // f64 stats region at ws start (12288 bytes), then f32 region.
  double* d64 = (double*)d_ws;
  double* sum1 = d64 + 0;      // 256
  double* sq1 = d64 + 256;
  double* sum2 = d64 + 512;
  double* sq2 = d64 + 768;
  double* sum3 = d64 + 1024;   // 128
  double* sq3 = d64 + 1152;
  double* hbarD = d64 + 1280;  // 128
  float* F = (float*)(d64 + 1536);

  size_t o = 0;
  float* y1 = F + o;   o += 10240000;  // 40000x256
  float* y2 = F + o;   o += 10240000;  // 40000x256
  float* y3 = F + o;   o += 5120000;   // 40000x128 (becomes h3 in place)
  float* Bbig = F + o; o += 2113536;   // 16512x128
  float* msum = F + o; o += 2560000;   // 20000x128
  float* cnt = F + o;  o += 20000;     // adjacent to msum: single memset
  float* msg = F + o;  o += 2560000;
  float* WihT = F + o; o += 49152;
  float* WhhT = F + o; o += 49152;
  float* Cov = F + o;  o += 16384;
  float* a4 = F + o;   o += 16384;
  float* nb4 = F + o;  o += 16384;
  float* a1 = F + o;   o += 256;
  float* b1 = F + o;   o += 256;
  float* a2 = F + o;   o += 256;
  float* b2 = F + o;   o += 256;
  float* a3 = F + o;   o += 128;
  float* b3 = F + o;   o += 128;
  float* hbarF = F + o; o += 128;
  // Temporal overlays (documented order-dependence):
  //  Spart lives in y1[0:2.62M)     (written K6, dead after K7b)
  //  U     lives in y1[2.62M:4.72M) (written K8a, dead after K8b)
  //  gi    lives in y1[2.56M:10.24M) (written after U dead)
  //  gh    lives in y2[0:7.68M);  hbarP in y2[7.68M:...)
  float* Spart = y1;                   // NSB*16384 = 2,621,440
  float* U = y1 + 2621440;             // 2,097,152
  float* gi = y1 + 2560000;            // 7,680,000 (ends exactly at y1 end)
  float* gh = y2;                      // 7,680,000
  float* hbarP = y2 + 7680000;         // NSB*128 = 20,480

  // zero f64 stats + msum/cnt
  hipMemsetAsync(d_ws, 0, 12288, stream);
  hipMemsetAsync(msum, 0, (2560000 + 20000) * sizeof(float), stream);

  k_transpose_gru<<<384, 256, 0, stream>>>(Wih, Whh, WihT, WhhT);

  // Edge MLP layers 1-3 with one-pass f64 BN stats
  k_edge_w1<<<2500, 256, 0, stream>>>(edge, W1, y1);
  k_colstats<<<256, 256, 0, stream>>>(y1, 40000, 256, sum1, sq1);
  k_finalize<<<1, 256, 0, stream>>>(sum1, sq1, g1, be1, a1, b1, 256, 1.0 / 40000.0);
  k_gemm<1><<<dim3(625, 2), 256, 0, stream>>>(y1, W2, y2, 40000, 256, 256, a1, b1, nullptr);
  k_colstats<<<256, 256, 0, stream>>>(y2, 40000, 256, sum2, sq2);
  k_finalize<<<1, 256, 0, stream>>>(sum2, sq2, g2, be2, a2, b2, 256, 1.0 / 40000.0);
  k_gemm<1><<<dim3(625, 1), 256, 0, stream>>>(y2, W3, y3, 40000, 256, 128, a2, b2, nullptr);
  k_colstats<<<256, 256, 0, stream>>>(y3, 40000, 128, sum3, sq3);
  k_finalize<<<1, 256, 0, stream>>>(sum3, sq3, g3, be3, a3, b3, 128, 1.0 / 40000.0);
  k_bnrelu_inplace<<<20000, 256, 0, stream>>>(y3, a3, b3, 5120000, 128);
  // y3 now holds h3

  // Layer-4 BN stats analytically: mu4 = hbar@W4, var4 = w^T Cov w
  k_cov_partials<<<NSB, 256, 0, stream>>>(y3, Spart, hbarP);
  k_hbar<<<1, 128, 0, stream>>>(hbarP, hbarD, hbarF);
  k_cov<<<64, 256, 0, stream>>>(Spart, hbarD, Cov);
  k_covW4<<<128, 256, 0, stream>>>(Cov, W4, U);
  k_a4nb4<<<64, 256, 0, stream>>>(W4, U, hbarF, g4, be4, a4, nb4);
  k_buildB<<<8256, 256, 0, stream>>>(W4, a4, nb4, Bbig);

  // Fused contraction + segment-sum scatter
  k_biggemm<<<1250, 256, 0, stream>>>(y3, node, eidx, Bbig, msum, cnt);

  // Segment mean + bias + relu, then GRU
  k_msg<<<10000, 256, 0, stream>>>(msum, cnt, bias, msg);
  k_gemm<0><<<dim3(313, 3), 256, 0, stream>>>(msg, WihT, gi, 20000, 128, 384, nullptr, nullptr, bih);
  k_gemm<0><<<dim3(313, 3), 256, 0, stream>>>(hidden, WhhT, gh, 20000, 128, 384, nullptr, nullptr, bhh);
  k_gru<<<10000, 256, 0, stream>>>(gi, gh, hidden, out);
}

// Round 4
// 1191.851 us; speedup vs baseline: 2.9001x; 2.9001x over previous
//
#include <hip/hip_runtime.h>
#include <cstdint>
#include <cstddef>

// Problem constants
#define N_NODE_C 20000
#define N_EDGE_C 40000
#define BN_EPS_F 1e-5f
#define NSB 160            // cov partial blocks (40000/160 = 250 rows each)
#define H3T_STRIDE 40064   // padded edge stride for h3T (313*128)

typedef __attribute__((ext_vector_type(8))) short bf16x8;
typedef __attribute__((ext_vector_type(16))) float f32x16;

// bf16 split helpers (RNE)
__device__ __forceinline__ ushort f2bf(float x) {
  unsigned u = __float_as_uint(x);
  unsigned r = u + 0x7fffu + ((u >> 16) & 1u);
  return (ushort)(r >> 16);
}
__device__ __forceinline__ float bf2f(ushort b) {
  return __uint_as_float(((unsigned)b) << 16);
}

__device__ __forceinline__ void gl_lds16(const ushort* g, ushort* l) {
  __builtin_amdgcn_global_load_lds(
      (const __attribute__((address_space(1))) unsigned int*)(g),
      (__attribute__((address_space(3))) unsigned int*)(l), 16, 0, 0);
}

// ---------------------------------------------------------------------------
// K0: transpose W_ih / W_hh (384x128 -> 128x384) so GRU GEMMs read B coalesced
__global__ __launch_bounds__(256) void k_transpose_gru(
    const float* __restrict__ Wih, const float* __restrict__ Whh,
    float* __restrict__ WihT, float* __restrict__ WhhT) {
  int i = blockIdx.x * 256 + threadIdx.x;           // 0..98303
  int which = i / 49152;
  int idx = i - which * 49152;                      // k*384+o
  int k = idx / 384, o = idx - k * 384;
  float v = which ? Whh[o * 128 + k] : Wih[o * 128 + k];
  if (which) WhhT[idx] = v; else WihT[idx] = v;
}

// ---------------------------------------------------------------------------
// K1: y1 = edge(40000x16) @ W1(16x256)
__global__ __launch_bounds__(256) void k_edge_w1(
    const float* __restrict__ edge, const float* __restrict__ W1,
    float* __restrict__ y1) {
  __shared__ float el[16][16];
  int e0 = blockIdx.x * 16;
  int t = threadIdx.x;
  el[t >> 4][t & 15] = edge[(size_t)e0 * 16 + t];
  __syncthreads();
  float w[16];
#pragma unroll
  for (int k = 0; k < 16; ++k) w[k] = W1[k * 256 + t];
#pragma unroll 4
  for (int e = 0; e < 16; ++e) {
    float acc = 0.f;
#pragma unroll
    for (int k = 0; k < 16; ++k) acc = fmaf(el[e][k], w[k], acc);
    y1[(size_t)(e0 + e) * 256 + t] = acc;
  }
}

// ---------------------------------------------------------------------------
// K2: per-column sum / sumsq (f64 atomics) of y[E x J], J in {128,256}
__global__ __launch_bounds__(256) void k_colstats(
    const float* __restrict__ y, int E, int J,
    double* __restrict__ sum, double* __restrict__ sumsq) {
  int t = threadIdx.x;
  int rpi = 256 / J;
  int col = t & (J - 1);
  int rof = t / J;
  double s = 0.0, q = 0.0;
  for (int r = blockIdx.x * rpi + rof; r < E; r += gridDim.x * rpi) {
    float v = y[(size_t)r * J + col];
    s += v;
    q += (double)v * (double)v;
  }
  atomicAdd(&sum[col], s);
  atomicAdd(&sumsq[col], q);
}

// K3: finalize BN affine per column: a = g*rsqrt(var+eps), b = be - mu*a
__global__ void k_finalize(const double* __restrict__ sum,
                           const double* __restrict__ sumsq,
                           const float* __restrict__ g,
                           const float* __restrict__ be,
                           float* __restrict__ a, float* __restrict__ b,
                           int J, double invE) {
  int j = threadIdx.x;
  if (j < J) {
    double mu = sum[j] * invE;
    double var = sumsq[j] * invE - mu * mu;
    float rstd = (float)(1.0 / sqrt(var + 1e-5));
    float aa = g[j] * rstd;
    a[j] = aa;
    b[j] = be[j] - (float)mu * aa;
  }
}

// ---------------------------------------------------------------------------
// K4: C[M,N] = T(A[M,K]) @ B[K,N] (+bias). MODE 1: T = relu(a*x+b) per A-col.
template <int MODE>
__global__ __launch_bounds__(256) void k_gemm(
    const float* __restrict__ A, const float* __restrict__ B,
    float* __restrict__ C, int M, int K, int N,
    const float* __restrict__ ta, const float* __restrict__ tb,
    const float* __restrict__ bias) {
  __shared__ float At[32][64];
  __shared__ float Bt[32][128];
  int mb = blockIdx.x * 64, nb = blockIdx.y * 128;
  int tid = threadIdx.x;
  int tr = tid >> 5, tc = tid & 31;
  float acc[8][4];
#pragma unroll
  for (int i = 0; i < 8; ++i)
#pragma unroll
    for (int j = 0; j < 4; ++j) acc[i][j] = 0.f;
  int arow = tid >> 2, akc = (tid & 3) * 8;
  int bkr = tid >> 3, bcol = (tid & 7) * 16;
  for (int k0 = 0; k0 < K; k0 += 32) {
    {
      int gr = mb + arow;
      float vv[8];
      if (gr < M) {
        float4 v0 = *(const float4*)&A[(size_t)gr * K + k0 + akc];
        float4 v1 = *(const float4*)&A[(size_t)gr * K + k0 + akc + 4];
        vv[0] = v0.x; vv[1] = v0.y; vv[2] = v0.z; vv[3] = v0.w;
        vv[4] = v1.x; vv[5] = v1.y; vv[6] = v1.z; vv[7] = v1.w;
      } else {
#pragma unroll
        for (int u = 0; u < 8; ++u) vv[u] = 0.f;
      }
#pragma unroll
      for (int u = 0; u < 8; ++u) {
        float x = vv[u];
        if (MODE == 1) {
          int k = k0 + akc + u;
          x = fmaxf(fmaf(x, ta[k], tb[k]), 0.f);
        }
        At[akc + u][arow] = x;
      }
    }
    {
      const float* src = &B[(size_t)(k0 + bkr) * N + nb + bcol];
      float4* d = (float4*)&Bt[bkr][bcol];
      d[0] = ((const float4*)src)[0];
      d[1] = ((const float4*)src)[1];
      d[2] = ((const float4*)src)[2];
      d[3] = ((const float4*)src)[3];
    }
    __syncthreads();
#pragma unroll 8
    for (int kk = 0; kk < 32; ++kk) {
      float4 a0 = *(float4*)&At[kk][tr * 8];
      float4 a1 = *(float4*)&At[kk][tr * 8 + 4];
      float4 b0 = *(float4*)&Bt[kk][tc * 4];
      float av[8] = {a0.x, a0.y, a0.z, a0.w, a1.x, a1.y, a1.z, a1.w};
      float bv[4] = {b0.x, b0.y, b0.z, b0.w};
#pragma unroll
      for (int i = 0; i < 8; ++i)
#pragma unroll
        for (int j = 0; j < 4; ++j)
          acc[i][j] = fmaf(av[i], bv[j], acc[i][j]);
    }
    __syncthreads();
  }
#pragma unroll
  for (int i = 0; i < 8; ++i) {
    int gr = mb + tr * 8 + i;
    if (gr < M) {
      int oc = nb + tc * 4;
      float4 o;
      o.x = acc[i][0]; o.y = acc[i][1]; o.z = acc[i][2]; o.w = acc[i][3];
      if (bias) {
        o.x += bias[oc]; o.y += bias[oc + 1];
        o.z += bias[oc + 2]; o.w += bias[oc + 3];
      }
      *(float4*)&C[(size_t)gr * N + oc] = o;
    }
  }
}

// ---------------------------------------------------------------------------
// K5: in-place h = relu(a*y + b) per column (J=128)
__global__ __launch_bounds__(256) void k_bnrelu_inplace(
    float* __restrict__ y, const float* __restrict__ a,
    const float* __restrict__ b, int n, int J) {
  int i = blockIdx.x * 256 + threadIdx.x;
  if (i < n) {
    int c = i & (J - 1);
    y[i] = fmaxf(fmaf(y[i], a[c], b[c]), 0.f);
  }
}

// ---------------------------------------------------------------------------
// K6: per-block partials of h3^T h3 (128x128) and column sums (Cov trick)
__global__ __launch_bounds__(256) void k_cov_partials(
    const float* __restrict__ h3, float* __restrict__ Spart,
    float* __restrict__ hbarP) {
  __shared__ float hl[2][128];
  int b = blockIdx.x;
  int t = threadIdx.x;
  int tr = t >> 4, tc = t & 15;
  float acc[8][8];
#pragma unroll
  for (int i = 0; i < 8; ++i)
#pragma unroll
    for (int j = 0; j < 8; ++j) acc[i][j] = 0.f;
  float cs = 0.f;
  int r0 = b * 250;
  for (int rs = 0; rs < 250; rs += 2) {
    hl[t >> 7][t & 127] = h3[(size_t)(r0 + rs + (t >> 7)) * 128 + (t & 127)];
    __syncthreads();
#pragma unroll
    for (int rr = 0; rr < 2; ++rr) {
      float a0[8], b0[8];
#pragma unroll
      for (int i = 0; i < 8; ++i) a0[i] = hl[rr][tr * 8 + i];
#pragma unroll
      for (int j = 0; j < 8; ++j) b0[j] = hl[rr][tc * 8 + j];
#pragma unroll
      for (int i = 0; i < 8; ++i)
#pragma unroll
        for (int j = 0; j < 8; ++j)
          acc[i][j] = fmaf(a0[i], b0[j], acc[i][j]);
    }
    if (t < 128) cs += hl[0][t] + hl[1][t];
    __syncthreads();
  }
  float* sp = &Spart[(size_t)b * 16384];
#pragma unroll
  for (int i = 0; i < 8; ++i)
#pragma unroll
    for (int j = 0; j < 8; j += 4) {
      float4 o;
      o.x = acc[i][j]; o.y = acc[i][j + 1];
      o.z = acc[i][j + 2]; o.w = acc[i][j + 3];
      *(float4*)&sp[(tr * 8 + i) * 128 + tc * 8 + j] = o;
    }
  if (t < 128) hbarP[b * 128 + t] = cs;
}

// K7a: hbar = (sum of partial colsums)/E  (f64)
__global__ void k_hbar(const float* __restrict__ hbarP,
                       double* __restrict__ hbarD, float* __restrict__ hbarF) {
  int t = threadIdx.x;  // 128
  double s = 0.0;
  for (int b = 0; b < NSB; ++b) s += (double)hbarP[b * 128 + t];
  s *= (1.0 / 40000.0);
  hbarD[t] = s;
  hbarF[t] = (float)s;
}

// K7b: Cov[k,l] = S/E - hbar_k*hbar_l
__global__ __launch_bounds__(256) void k_cov(
    const float* __restrict__ Spart, const double* __restrict__ hbarD,
    float* __restrict__ Cov) {
  int i = blockIdx.x * 256 + threadIdx.x;  // < 16384
  int k = i >> 7, l = i & 127;
  double s = 0.0;
  for (int b = 0; b < NSB; ++b) s += (double)Spart[(size_t)b * 16384 + i];
  Cov[i] = (float)(s * (1.0 / 40000.0) - hbarD[k] * hbarD[l]);
}

// K8a: U = Cov @ W4  (128 x 16384)
__global__ __launch_bounds__(256) void k_covW4(
    const float* __restrict__ Cov, const float* __restrict__ W4,
    float* __restrict__ U) {
  __shared__ float cl[8][128];
  int bk = blockIdx.x & 15, bj = blockIdx.x >> 4;
  int k0 = bk * 8, j0 = bj * 2048;
  int t = threadIdx.x;
  {
    float4 v = *(const float4*)&Cov[(size_t)(k0 + (t >> 5)) * 128 + (t & 31) * 4];
    *(float4*)&cl[t >> 5][(t & 31) * 4] = v;
  }
  __syncthreads();
  for (int ji = 0; ji < 8; ++ji) {
    int j = j0 + ji * 256 + t;
    float acc[8];
#pragma unroll
    for (int i = 0; i < 8; ++i) acc[i] = 0.f;
#pragma unroll 4
    for (int l = 0; l < 128; ++l) {
      float w = W4[(size_t)l * 16384 + j];
#pragma unroll
      for (int i = 0; i < 8; ++i) acc[i] = fmaf(cl[i][l], w, acc[i]);
    }
#pragma unroll
    for (int i = 0; i < 8; ++i) U[(size_t)(k0 + i) * 16384 + j] = acc[i];
  }
}

// K8b: mu4/var4 -> a4, nb4
__global__ __launch_bounds__(256) void k_a4nb4(
    const float* __restrict__ W4, const float* __restrict__ U,
    const float* __restrict__ hbarF, const float* __restrict__ g4,
    const float* __restrict__ be4, float* __restrict__ a4,
    float* __restrict__ nb4) {
  __shared__ float hb[128];
  int t = threadIdx.x;
  if (t < 128) hb[t] = hbarF[t];
  __syncthreads();
  int j = blockIdx.x * 256 + t;
  float macc = 0.f, vacc = 0.f;
#pragma unroll 4
  for (int k = 0; k < 128; ++k) {
    float w = W4[(size_t)k * 16384 + j];
    macc = fmaf(hb[k], w, macc);
    vacc = fmaf(w, U[(size_t)k * 16384 + j], vacc);
  }
  float aa = g4[j] * (1.0f / sqrtf(vacc + BN_EPS_F));
  a4[j] = aa;
  nb4[j] = be4[j] - macc * aa;
}

// ---------------------------------------------------------------------------
// K9a: split node into bf16 hi/lo (nodeH, nodeL), 2.56M elems, 4/thread
__global__ __launch_bounds__(256) void k_split_node(
    const float* __restrict__ node, ushort* __restrict__ nH,
    ushort* __restrict__ nL) {
  int i = blockIdx.x * 256 + threadIdx.x;  // grid 2500 -> 640000 threads
  int base = i * 4;
  float4 v = *(const float4*)&node[base];
  ushort4 h, lo;
  float x;
  x = v.x; h.x = f2bf(x); lo.x = f2bf(x - bf2f(h.x));
  x = v.y; h.y = f2bf(x); lo.y = f2bf(x - bf2f(h.y));
  x = v.z; h.z = f2bf(x); lo.z = f2bf(x - bf2f(h.z));
  x = v.w; h.w = f2bf(x); lo.w = f2bf(x - bf2f(h.w));
  *(ushort4*)&nH[base] = h;
  *(ushort4*)&nL[base] = lo;
}

// K9b: h3T[k][e] = h3[e][k], zero-padded to H3T_STRIDE edges (tiled transpose)
__global__ __launch_bounds__(256) void k_h3T(const float* __restrict__ y3,
                                             float* __restrict__ h3T) {
  __shared__ float tile[32][33];
  int bx = blockIdx.x;  // 1252 e-tiles
  int by = blockIdx.y;  // 4 k-tiles
  int tx = threadIdx.x & 31, ty = threadIdx.x >> 5;  // 32 x 8
#pragma unroll
  for (int i = 0; i < 4; ++i) {
    int e = bx * 32 + ty + 8 * i;
    float v = (e < 40000) ? y3[(size_t)e * 128 + by * 32 + tx] : 0.f;
    tile[ty + 8 * i][tx] = v;  // tile[e_local][k_local]
  }
  __syncthreads();
#pragma unroll
  for (int i = 0; i < 4; ++i) {
    int kk = by * 32 + ty + 8 * i;
    h3T[(size_t)kk * H3T_STRIDE + bx * 32 + tx] = tile[tx][ty + 8 * i];
  }
}

// K9c: build B2 packed in MFMA (32x32x16 bf16) B-fragment order, split hi/lo.
//   logical B_k[d][f] = W4[k*16384 + d*128 + f] * a4[d*128+f]  (k<128)
//              B_128[d][f] = nb4[d*128+f]                       (bias tail)
//   layout: per (k, H=f-half): 16384 bf16 = [dstep 8][cgg 2][s 2][lane 64][j 8]
//   with d = dstep*16 + (lane>>5)*8 + j, f = H*64 + cgg*32 + (lane&31)
//   B fragment layout: k_local = (lane>>5)*8 + j, col = lane&31 (CDNA conv.)
__global__ __launch_bounds__(256) void k_buildB2(
    const float* __restrict__ W4, const float* __restrict__ a4,
    const float* __restrict__ nb4, ushort* __restrict__ B2) {
  int tid = blockIdx.x * 256 + threadIdx.x;  // exact 2,113,536 (grid 8256)
  int k = tid >> 14;            // 0..128
  int rem = tid & 16383;
  int H = rem >> 13;
  int rem2 = rem & 8191;
  int j = rem2 & 7;
  int lane = (rem2 >> 3) & 63;
  int cgg = (rem2 >> 9) & 1;
  int dstep = rem2 >> 10;       // 0..7
  int d = dstep * 16 + (lane >> 5) * 8 + j;
  int f = H * 64 + cgg * 32 + (lane & 31);
  int df = d * 128 + f;
  float v;
  if (k < 128) v = W4[(size_t)k * 16384 + df] * a4[df];
  else v = nb4[df];
  ushort hi = f2bf(v);
  ushort lo = f2bf(v - bf2f(hi));
  size_t base = ((size_t)(k * 2 + H)) * 16384 +
                (size_t)((dstep * 2 + cgg) * 2) * 512 + lane * 8 + j;
  B2[base] = hi;
  B2[base + 512] = lo;
}

// ---------------------------------------------------------------------------
// K10: MFMA contraction. message = sum_k h3[:,k] * (X @ B_k) + X @ C4,
// X = node[src] split bf16 hi/lo (split-3: Xh*Bh + Xh*Bl + Xl*Bh).
// Block: 512 thr (8 waves), BM=128 edges, BN=64 f (grid.y halves), wave =
// (rg=w>>1 rows 32*rg, cg=w&1 cols 32*cg). One 32x32 MFMA tile per wave.
// B_k chunk (32KB) double-buffered via global_load_lds, 2-phase pipeline.
// Epilogue: atomic segment-sum into msum (+ cnt on y==0).
__global__ __launch_bounds__(512) void k_biggemm2(
    const ushort* __restrict__ nodeH, const ushort* __restrict__ nodeL,
    const ushort* __restrict__ B2, const float* __restrict__ h3T,
    const int* __restrict__ eidx, float* __restrict__ msum,
    float* __restrict__ cnt) {
  __shared__ ushort Bl[2][16384];   // 64KB
  __shared__ int sidx[128], didx[128];
  const int t = threadIdx.x;
  const int e0 = blockIdx.x * 128;
  const int H = blockIdx.y;
  const int w = t >> 6;
  const int l = t & 63;
  const int rg = w >> 1;
  const int cg = w & 1;
  const int dg = l >> 5;  // 0/1

  if (t < 256) {
    int e = e0 + (t >> 1);
    int v = (e < 40000) ? eidx[(size_t)e * 2 + (t & 1)] : 0;
    if (t & 1) didx[t >> 1] = v; else sidx[t >> 1] = v;
  }
  // stage k=0 chunk
  {
    const ushort* src = B2 + (size_t)H * 16384 + w * 2048 + l * 8;
#pragma unroll
    for (int i = 0; i < 4; ++i)
      gl_lds16(src + i * 512, &Bl[0][w * 2048 + i * 512]);
  }
  __syncthreads();  // sidx ready; own stage loads drained by barrier's vmcnt

  // per-lane X fragments (row = rg*32 + (l&31), d = ds*16 + dg*8 + j)
  const int myrow = rg * 32 + (l & 31);
  const int esrc = sidx[myrow];
  bf16x8 xh[8], xl[8];
  {
    const ushort* ph = nodeH + (size_t)esrc * 128 + dg * 8;
    const ushort* pl_ = nodeL + (size_t)esrc * 128 + dg * 8;
#pragma unroll
    for (int ds_ = 0; ds_ < 8; ++ds_) {
      xh[ds_] = *(const bf16x8*)(ph + ds_ * 16);
      xl[ds_] = *(const bf16x8*)(pl_ + ds_ * 16);
    }
  }

  f32x16 msg;
#pragma unroll
  for (int r = 0; r < 16; ++r) msg[r] = 0.f;

  for (int k = 0; k <= 128; ++k) {
    const int buf = k & 1;
    // prefetch chunk k+1 into other buffer (lands before next barrier)
    if (k < 128) {
      const ushort* src = B2 + ((size_t)((k + 1) * 2 + H)) * 16384 + w * 2048 + l * 8;
#pragma unroll
      for (int i = 0; i < 4; ++i)
        gl_lds16(src + i * 512, &Bl[buf ^ 1][w * 2048 + i * 512]);
    }
    // h weights (issue early; k==128 is the bias row, h == 1)
    float4 hv[4];
    if (k < 128) {
      const float* hb = h3T + (size_t)k * H3T_STRIDE + e0 + rg * 32 + 4 * dg;
#pragma unroll
      for (int q = 0; q < 4; ++q) hv[q] = *(const float4*)(hb + q * 8);
    } else {
#pragma unroll
      for (int q = 0; q < 4; ++q) hv[q] = make_float4(1.f, 1.f, 1.f, 1.f);
    }
    f32x16 u;
#pragma unroll
    for (int r = 0; r < 16; ++r) u[r] = 0.f;
    const ushort* bbase = &Bl[buf][0];
#pragma unroll
    for (int ds_ = 0; ds_ < 8; ++ds_) {
      int fo = ((ds_ * 2 + cg) * 2) * 512 + l * 8;
      bf16x8 bh = *(const bf16x8*)(bbase + fo);
      bf16x8 bl2 = *(const bf16x8*)(bbase + fo + 512);
      u = __builtin_amdgcn_mfma_f32_32x32x16_bf16(xh[ds_], bh, u, 0, 0, 0);
      u = __builtin_amdgcn_mfma_f32_32x32x16_bf16(xh[ds_], bl2, u, 0, 0, 0);
      u = __builtin_amdgcn_mfma_f32_32x32x16_bf16(xl[ds_], bh, u, 0, 0, 0);
    }
#pragma unroll
    for (int r = 0; r < 16; ++r) {
      float hval = ((const float*)&hv[r >> 2])[r & 3];
      msg[r] = fmaf(hval, u[r], msg[r]);
    }
    __syncthreads();  // waves done reading Bl[buf]; own prefetch drained
  }

  // epilogue: C layout row=(r&3)+8*(r>>2)+4*dg, col=l&31 (m74/m101 verified)
  const int fbase = H * 64 + cg * 32 + (l & 31);
#pragma unroll
  for (int r = 0; r < 16; ++r) {
    int lrow = rg * 32 + (r & 3) + 8 * (r >> 2) + 4 * dg;
    int ge = e0 + lrow;
    if (ge < 40000)
      atomicAdd(&msum[(size_t)didx[lrow] * 128 + fbase], msg[r]);
  }
  if (blockIdx.y == 0 && t < 128) {
    int ge = e0 + t;
    if (ge < 40000) atomicAdd(&cnt[didx[t]], 1.0f);
  }
}

// ---------------------------------------------------------------------------
// K11: msg = relu(msum/max(cnt,1) + bias)
__global__ __launch_bounds__(256) void k_msg(
    const float* __restrict__ msum, const float* __restrict__ cnt,
    const float* __restrict__ bias, float* __restrict__ msg) {
  int i = blockIdx.x * 256 + threadIdx.x;  // exact 2,560,000
  int nn = i >> 7, f = i & 127;
  float m = msum[i] / fmaxf(cnt[nn], 1.0f);
  msg[i] = fmaxf(m + bias[f], 0.f);
}

// K12: GRU gates -> h1, written twice (tuple output h1, h1[None])
__global__ __launch_bounds__(256) void k_gru(
    const float* __restrict__ gi, const float* __restrict__ gh,
    const float* __restrict__ h0, float* __restrict__ out) {
  int i = blockIdx.x * 256 + threadIdx.x;  // exact 2,560,000
  int nn = i >> 7, f = i & 127;
  size_t base = (size_t)nn * 384;
  float ir = gi[base + f], hr = gh[base + f];
  float iz = gi[base + 128 + f], hz = gh[base + 128 + f];
  float in_ = gi[base + 256 + f], hn = gh[base + 256 + f];
  float r = 1.f / (1.f + expf(-(ir + hr)));
  float z = 1.f / (1.f + expf(-(iz + hz)));
  float n = tanhf(in_ + r * hn);
  float h1 = (1.f - z) * n + z * h0[i];
  out[i] = h1;
  out[2560000 + i] = h1;
}

// ---------------------------------------------------------------------------
extern "C" void kernel_launch(void* const* d_in, const int* in_sizes, int n_in,
                              void* d_out, int out_size, void* d_ws,
                              size_t ws_size, hipStream_t stream) {
  (void)in_sizes; (void)n_in; (void)out_size; (void)ws_size;
  const float* node = (const float*)d_in[0];
  const int* eidx = (const int*)d_in[1];
  const float* edge = (const float*)d_in[2];
  const float* hidden = (const float*)d_in[3];
  const float* W1 = (const float*)d_in[4];
  const float* g1 = (const float*)d_in[5];
  const float* be1 = (const float*)d_in[6];
  const float* W2 = (const float*)d_in[7];
  const float* g2 = (const float*)d_in[8];
  const float* be2 = (const float*)d_in[9];
  const float* W3 = (const float*)d_in[10];
  const float* g3 = (const float*)d_in[11];
  const float* be3 = (const float*)d_in[12];
  const float* W4 = (const float*)d_in[13];
  const float* g4 = (const float*)d_in[14];
  const float* be4 = (const float*)d_in[15];
  const float* bias = (const float*)d_in[16];
  const float* Wih = (const float*)d_in[17];
  const float* Whh = (const float*)d_in[18];
  const float* bih = (const float*)d_in[19];
  const float* bhh = (const float*)d_in[20];
  float* out = (float*)d_out;

  // f64 stats region at ws start (12288 bytes), then f32 region.
  double* d64 = (double*)d_ws;
  double* sum1 = d64 + 0;
  double* sq1 = d64 + 256;
  double* sum2 = d64 + 512;
  double* sq2 = d64 + 768;
  double* sum3 = d64 + 1024;
  double* sq3 = d64 + 1152;
  double* hbarD = d64 + 1280;
  float* F = (float*)(d64 + 1536);

  size_t o = 0;
  float* y1 = F + o;   o += 10240000;  // 40000x256
  float* y2 = F + o;   o += 10240000;  // 40000x256
  float* y3 = F + o;   o += 5120000;   // 40000x128 (becomes h3)
  float* B2f = F + o;  o += 2113536;   // 129*2*16384 bf16 = same slot size
  float* msum = F + o; o += 2560000;
  float* cnt = F + o;  o += 20000;
  float* msg = F + o;  o += 2560000;
  float* WihT = F + o; o += 49152;
  float* WhhT = F + o; o += 49152;
  float* Cov = F + o;  o += 16384;
  float* a4 = F + o;   o += 16384;
  float* nb4 = F + o;  o += 16384;
  float* a1 = F + o;   o += 256;
  float* b1 = F + o;   o += 256;
  float* a2 = F + o;   o += 256;
  float* b2 = F + o;   o += 256;
  float* a3 = F + o;   o += 128;
  float* b3 = F + o;   o += 128;
  float* hbarF = F + o; o += 128;
  // Temporal overlays (order-dependent; producers AND consumers checked):
  //  Spart  = y1[0:2.62M)      written K6 (after y1's last read by k_gemm L2),
  //                            dead after K7b
  //  U      = y1[2.62M:4.72M)  written K8a, dead after K8b
  //  gi     = y1[2.56M:10.24M) written after biggemm2 (Spart/U dead)
  //  h3T    = y2[0:5.13M)      written K9b (after y2's last read by k_gemm L3),
  //                            dead after biggemm2
  //  hbarP  = y2[7.68M:7.70M)  disjoint from h3T
  //  gh     = y2[0:7.68M)      written after biggemm2 (h3T dead)
  //  nodeHL = msg slot (2.56M floats = 2x2.56M ushorts): written by
  //           k_split_node FIRST, no other producer touches msg until k_msg,
  //           which runs after biggemm2 (nodeHL dead by then).
  //           (Round-3 NaN root cause: nodeHL previously sat inside y1 and
  //            was clobbered by k_edge_w1's full-y1 write.)
  float* Spart = y1;
  float* U = y1 + 2621440;
  float* gi = y1 + 2560000;
  float* h3T = y2;                            // 128 x 40064
  float* gh = y2;
  float* hbarP = y2 + 7680000;
  ushort* nodeH = (ushort*)msg;               // 2,560,000 ushorts
  ushort* nodeL = ((ushort*)msg) + 2560000;   // 2,560,000 ushorts
  ushort* B2 = (ushort*)B2f;

  hipMemsetAsync(d_ws, 0, 12288, stream);
  hipMemsetAsync(msum, 0, (2560000 + 20000) * sizeof(float), stream);

  k_transpose_gru<<<384, 256, 0, stream>>>(Wih, Whh, WihT, WhhT);
  k_split_node<<<2500, 256, 0, stream>>>(node, nodeH, nodeL);

  // Edge MLP layers 1-3 with one-pass f64 BN stats
  k_edge_w1<<<2500, 256, 0, stream>>>(edge, W1, y1);
  k_colstats<<<256, 256, 0, stream>>>(y1, 40000, 256, sum1, sq1);
  k_finalize<<<1, 256, 0, stream>>>(sum1, sq1, g1, be1, a1, b1, 256, 1.0 / 40000.0);
  k_gemm<1><<<dim3(625, 2), 256, 0, stream>>>(y1, W2, y2, 40000, 256, 256, a1, b1, nullptr);
  k_colstats<<<256, 256, 0, stream>>>(y2, 40000, 256, sum2, sq2);
  k_finalize<<<1, 256, 0, stream>>>(sum2, sq2, g2, be2, a2, b2, 256, 1.0 / 40000.0);
  k_gemm<1><<<dim3(625, 1), 256, 0, stream>>>(y2, W3, y3, 40000, 256, 128, a2, b2, nullptr);
  k_colstats<<<256, 256, 0, stream>>>(y3, 40000, 128, sum3, sq3);
  k_finalize<<<1, 256, 0, stream>>>(sum3, sq3, g3, be3, a3, b3, 128, 1.0 / 40000.0);
  k_bnrelu_inplace<<<20000, 256, 0, stream>>>(y3, a3, b3, 5120000, 128);
  // y3 now holds h3

  // h3T (y2's MLP contents are dead now)
  k_h3T<<<dim3(1252, 4), 256, 0, stream>>>(y3, h3T);

  // Layer-4 BN stats analytically: mu4 = hbar@W4, var4 = w^T Cov w
  k_cov_partials<<<NSB, 256, 0, stream>>>(y3, Spart, hbarP);
  k_hbar<<<1, 128, 0, stream>>>(hbarP, hbarD, hbarF);
  k_cov<<<64, 256, 0, stream>>>(Spart, hbarD, Cov);
  k_covW4<<<128, 256, 0, stream>>>(Cov, W4, U);
  k_a4nb4<<<64, 256, 0, stream>>>(W4, U, hbarF, g4, be4, a4, nb4);
  k_buildB2<<<8256, 256, 0, stream>>>(W4, a4, nb4, B2);

  // MFMA contraction + segment-sum scatter
  k_biggemm2<<<dim3(313, 2), 512, 0, stream>>>(nodeH, nodeL, B2, h3T, eidx,
                                               msum, cnt);

  // Segment mean + bias + relu, then GRU
  k_msg<<<10000, 256, 0, stream>>>(msum, cnt, bias, msg);
  k_gemm<0><<<dim3(313, 3), 256, 0, stream>>>(msg, WihT, gi, 20000, 128, 384, nullptr, nullptr, bih);
  k_gemm<0><<<dim3(313, 3), 256, 0, stream>>>(hidden, WhhT, gh, 20000, 128, 384, nullptr, nullptr, bhh);
  k_gru<<<10000, 256, 0, stream>>>(gi, gh, hidden, out);
}

// Round 5
// 875.809 us; speedup vs baseline: 3.9467x; 1.3609x over previous
//
#include <hip/hip_runtime.h>
#include <cstdint>
#include <cstddef>

// Problem constants
#define N_NODE_C 20000
#define N_EDGE_C 40000
#define BN_EPS_F 1e-5f
#define NSB 160            // cov partial blocks (40000/160 = 250 rows each)
#define H3T_STRIDE 40064   // padded edge stride for h3T (313*128)

typedef __attribute__((ext_vector_type(8))) short bf16x8;
typedef __attribute__((ext_vector_type(16))) float f32x16;

// bf16 split helpers (RNE)
__device__ __forceinline__ ushort f2bf(float x) {
  unsigned u = __float_as_uint(x);
  unsigned r = u + 0x7fffu + ((u >> 16) & 1u);
  return (ushort)(r >> 16);
}
__device__ __forceinline__ float bf2f(ushort b) {
  return __uint_as_float(((unsigned)b) << 16);
}

__device__ __forceinline__ void gl_lds16(const ushort* g, ushort* l) {
  __builtin_amdgcn_global_load_lds(
      (const __attribute__((address_space(1))) unsigned int*)(g),
      (__attribute__((address_space(3))) unsigned int*)(l), 16, 0, 0);
}

// ---------------------------------------------------------------------------
// K0: transpose W_ih / W_hh (384x128 -> 128x384) so GRU GEMMs read B coalesced
__global__ __launch_bounds__(256) void k_transpose_gru(
    const float* __restrict__ Wih, const float* __restrict__ Whh,
    float* __restrict__ WihT, float* __restrict__ WhhT) {
  int i = blockIdx.x * 256 + threadIdx.x;           // 0..98303
  int which = i / 49152;
  int idx = i - which * 49152;                      // k*384+o
  int k = idx / 384, o = idx - k * 384;
  float v = which ? Whh[o * 128 + k] : Wih[o * 128 + k];
  if (which) WhhT[idx] = v; else WihT[idx] = v;
}

// ---------------------------------------------------------------------------
// K1: y1 = edge(40000x16) @ W1(16x256)
__global__ __launch_bounds__(256) void k_edge_w1(
    const float* __restrict__ edge, const float* __restrict__ W1,
    float* __restrict__ y1) {
  __shared__ float el[16][16];
  int e0 = blockIdx.x * 16;
  int t = threadIdx.x;
  el[t >> 4][t & 15] = edge[(size_t)e0 * 16 + t];
  __syncthreads();
  float w[16];
#pragma unroll
  for (int k = 0; k < 16; ++k) w[k] = W1[k * 256 + t];
#pragma unroll 4
  for (int e = 0; e < 16; ++e) {
    float acc = 0.f;
#pragma unroll
    for (int k = 0; k < 16; ++k) acc = fmaf(el[e][k], w[k], acc);
    y1[(size_t)(e0 + e) * 256 + t] = acc;
  }
}

// ---------------------------------------------------------------------------
// K2: per-column sum / sumsq (f64 atomics) of y[E x J], J in {128,256}
__global__ __launch_bounds__(256) void k_colstats(
    const float* __restrict__ y, int E, int J,
    double* __restrict__ sum, double* __restrict__ sumsq) {
  int t = threadIdx.x;
  int rpi = 256 / J;
  int col = t & (J - 1);
  int rof = t / J;
  double s = 0.0, q = 0.0;
  for (int r = blockIdx.x * rpi + rof; r < E; r += gridDim.x * rpi) {
    float v = y[(size_t)r * J + col];
    s += v;
    q += (double)v * (double)v;
  }
  atomicAdd(&sum[col], s);
  atomicAdd(&sumsq[col], q);
}

// K3: finalize BN affine per column: a = g*rsqrt(var+eps), b = be - mu*a
__global__ void k_finalize(const double* __restrict__ sum,
                           const double* __restrict__ sumsq,
                           const float* __restrict__ g,
                           const float* __restrict__ be,
                           float* __restrict__ a, float* __restrict__ b,
                           int J, double invE) {
  int j = threadIdx.x;
  if (j < J) {
    double mu = sum[j] * invE;
    double var = sumsq[j] * invE - mu * mu;
    float rstd = (float)(1.0 / sqrt(var + 1e-5));
    float aa = g[j] * rstd;
    a[j] = aa;
    b[j] = be[j] - (float)mu * aa;
  }
}

// ---------------------------------------------------------------------------
// K4: C[M,N] = T(A[M,K]) @ B[K,N] (+bias). MODE 1: T = relu(a*x+b) per A-col.
template <int MODE>
__global__ __launch_bounds__(256) void k_gemm(
    const float* __restrict__ A, const float* __restrict__ B,
    float* __restrict__ C, int M, int K, int N,
    const float* __restrict__ ta, const float* __restrict__ tb,
    const float* __restrict__ bias) {
  __shared__ float At[32][64];
  __shared__ float Bt[32][128];
  int mb = blockIdx.x * 64, nb = blockIdx.y * 128;
  int tid = threadIdx.x;
  int tr = tid >> 5, tc = tid & 31;
  float acc[8][4];
#pragma unroll
  for (int i = 0; i < 8; ++i)
#pragma unroll
    for (int j = 0; j < 4; ++j) acc[i][j] = 0.f;
  int arow = tid >> 2, akc = (tid & 3) * 8;
  int bkr = tid >> 3, bcol = (tid & 7) * 16;
  for (int k0 = 0; k0 < K; k0 += 32) {
    {
      int gr = mb + arow;
      float vv[8];
      if (gr < M) {
        float4 v0 = *(const float4*)&A[(size_t)gr * K + k0 + akc];
        float4 v1 = *(const float4*)&A[(size_t)gr * K + k0 + akc + 4];
        vv[0] = v0.x; vv[1] = v0.y; vv[2] = v0.z; vv[3] = v0.w;
        vv[4] = v1.x; vv[5] = v1.y; vv[6] = v1.z; vv[7] = v1.w;
      } else {
#pragma unroll
        for (int u = 0; u < 8; ++u) vv[u] = 0.f;
      }
#pragma unroll
      for (int u = 0; u < 8; ++u) {
        float x = vv[u];
        if (MODE == 1) {
          int k = k0 + akc + u;
          x = fmaxf(fmaf(x, ta[k], tb[k]), 0.f);
        }
        At[akc + u][arow] = x;
      }
    }
    {
      const float* src = &B[(size_t)(k0 + bkr) * N + nb + bcol];
      float4* d = (float4*)&Bt[bkr][bcol];
      d[0] = ((const float4*)src)[0];
      d[1] = ((const float4*)src)[1];
      d[2] = ((const float4*)src)[2];
      d[3] = ((const float4*)src)[3];
    }
    __syncthreads();
#pragma unroll 8
    for (int kk = 0; kk < 32; ++kk) {
      float4 a0 = *(float4*)&At[kk][tr * 8];
      float4 a1 = *(float4*)&At[kk][tr * 8 + 4];
      float4 b0 = *(float4*)&Bt[kk][tc * 4];
      float av[8] = {a0.x, a0.y, a0.z, a0.w, a1.x, a1.y, a1.z, a1.w};
      float bv[4] = {b0.x, b0.y, b0.z, b0.w};
#pragma unroll
      for (int i = 0; i < 8; ++i)
#pragma unroll
        for (int j = 0; j < 4; ++j)
          acc[i][j] = fmaf(av[i], bv[j], acc[i][j]);
    }
    __syncthreads();
  }
#pragma unroll
  for (int i = 0; i < 8; ++i) {
    int gr = mb + tr * 8 + i;
    if (gr < M) {
      int oc = nb + tc * 4;
      float4 o;
      o.x = acc[i][0]; o.y = acc[i][1]; o.z = acc[i][2]; o.w = acc[i][3];
      if (bias) {
        o.x += bias[oc]; o.y += bias[oc + 1];
        o.z += bias[oc + 2]; o.w += bias[oc + 3];
      }
      *(float4*)&C[(size_t)gr * N + oc] = o;
    }
  }
}

// ---------------------------------------------------------------------------
// K5: in-place h = relu(a*y + b) per column (J=128)
__global__ __launch_bounds__(256) void k_bnrelu_inplace(
    float* __restrict__ y, const float* __restrict__ a,
    const float* __restrict__ b, int n, int J) {
  int i = blockIdx.x * 256 + threadIdx.x;
  if (i < n) {
    int c = i & (J - 1);
    y[i] = fmaxf(fmaf(y[i], a[c], b[c]), 0.f);
  }
}

// ---------------------------------------------------------------------------
// K6: per-block partials of h3^T h3 (128x128) and column sums (Cov trick)
__global__ __launch_bounds__(256) void k_cov_partials(
    const float* __restrict__ h3, float* __restrict__ Spart,
    float* __restrict__ hbarP) {
  __shared__ float hl[2][128];
  int b = blockIdx.x;
  int t = threadIdx.x;
  int tr = t >> 4, tc = t & 15;
  float acc[8][8];
#pragma unroll
  for (int i = 0; i < 8; ++i)
#pragma unroll
    for (int j = 0; j < 8; ++j) acc[i][j] = 0.f;
  float cs = 0.f;
  int r0 = b * 250;
  for (int rs = 0; rs < 250; rs += 2) {
    hl[t >> 7][t & 127] = h3[(size_t)(r0 + rs + (t >> 7)) * 128 + (t & 127)];
    __syncthreads();
#pragma unroll
    for (int rr = 0; rr < 2; ++rr) {
      float a0[8], b0[8];
#pragma unroll
      for (int i = 0; i < 8; ++i) a0[i] = hl[rr][tr * 8 + i];
#pragma unroll
      for (int j = 0; j < 8; ++j) b0[j] = hl[rr][tc * 8 + j];
#pragma unroll
      for (int i = 0; i < 8; ++i)
#pragma unroll
        for (int j = 0; j < 8; ++j)
          acc[i][j] = fmaf(a0[i], b0[j], acc[i][j]);
    }
    if (t < 128) cs += hl[0][t] + hl[1][t];
    __syncthreads();
  }
  float* sp = &Spart[(size_t)b * 16384];
#pragma unroll
  for (int i = 0; i < 8; ++i)
#pragma unroll
    for (int j = 0; j < 8; j += 4) {
      float4 o;
      o.x = acc[i][j]; o.y = acc[i][j + 1];
      o.z = acc[i][j + 2]; o.w = acc[i][j + 3];
      *(float4*)&sp[(tr * 8 + i) * 128 + tc * 8 + j] = o;
    }
  if (t < 128) hbarP[b * 128 + t] = cs;
}

// K7a: hbar = (sum of partial colsums)/E  (f64)
__global__ void k_hbar(const float* __restrict__ hbarP,
                       double* __restrict__ hbarD, float* __restrict__ hbarF) {
  int t = threadIdx.x;  // 128
  double s = 0.0;
  for (int b = 0; b < NSB; ++b) s += (double)hbarP[b * 128 + t];
  s *= (1.0 / 40000.0);
  hbarD[t] = s;
  hbarF[t] = (float)s;
}

// K7b: Cov[k,l] = S/E - hbar_k*hbar_l
__global__ __launch_bounds__(256) void k_cov(
    const float* __restrict__ Spart, const double* __restrict__ hbarD,
    float* __restrict__ Cov) {
  int i = blockIdx.x * 256 + threadIdx.x;  // < 16384
  int k = i >> 7, l = i & 127;
  double s = 0.0;
  for (int b = 0; b < NSB; ++b) s += (double)Spart[(size_t)b * 16384 + i];
  Cov[i] = (float)(s * (1.0 / 40000.0) - hbarD[k] * hbarD[l]);
}

// K8a: U = Cov @ W4  (128 x 16384)
__global__ __launch_bounds__(256) void k_covW4(
    const float* __restrict__ Cov, const float* __restrict__ W4,
    float* __restrict__ U) {
  __shared__ float cl[8][128];
  int bk = blockIdx.x & 15, bj = blockIdx.x >> 4;
  int k0 = bk * 8, j0 = bj * 2048;
  int t = threadIdx.x;
  {
    float4 v = *(const float4*)&Cov[(size_t)(k0 + (t >> 5)) * 128 + (t & 31) * 4];
    *(float4*)&cl[t >> 5][(t & 31) * 4] = v;
  }
  __syncthreads();
  for (int ji = 0; ji < 8; ++ji) {
    int j = j0 + ji * 256 + t;
    float acc[8];
#pragma unroll
    for (int i = 0; i < 8; ++i) acc[i] = 0.f;
#pragma unroll 4
    for (int l = 0; l < 128; ++l) {
      float w = W4[(size_t)l * 16384 + j];
#pragma unroll
      for (int i = 0; i < 8; ++i) acc[i] = fmaf(cl[i][l], w, acc[i]);
    }
#pragma unroll
    for (int i = 0; i < 8; ++i) U[(size_t)(k0 + i) * 16384 + j] = acc[i];
  }
}

// K8b: mu4/var4 -> a4, nb4
__global__ __launch_bounds__(256) void k_a4nb4(
    const float* __restrict__ W4, const float* __restrict__ U,
    const float* __restrict__ hbarF, const float* __restrict__ g4,
    const float* __restrict__ be4, float* __restrict__ a4,
    float* __restrict__ nb4) {
  __shared__ float hb[128];
  int t = threadIdx.x;
  if (t < 128) hb[t] = hbarF[t];
  __syncthreads();
  int j = blockIdx.x * 256 + t;
  float macc = 0.f, vacc = 0.f;
#pragma unroll 4
  for (int k = 0; k < 128; ++k) {
    float w = W4[(size_t)k * 16384 + j];
    macc = fmaf(hb[k], w, macc);
    vacc = fmaf(w, U[(size_t)k * 16384 + j], vacc);
  }
  float aa = g4[j] * (1.0f / sqrtf(vacc + BN_EPS_F));
  a4[j] = aa;
  nb4[j] = be4[j] - macc * aa;
}

// ---------------------------------------------------------------------------
// K9a: split node into bf16 hi/lo (nodeH, nodeL), 2.56M elems, 4/thread
// (nodeL currently unused by the contraction — kept as fallback for a
//  split-2 re-add if absmax ever fails; costs ~3 us.)
__global__ __launch_bounds__(256) void k_split_node(
    const float* __restrict__ node, ushort* __restrict__ nH,
    ushort* __restrict__ nL) {
  int i = blockIdx.x * 256 + threadIdx.x;  // grid 2500 -> 640000 threads
  int base = i * 4;
  float4 v = *(const float4*)&node[base];
  ushort4 h, lo;
  float x;
  x = v.x; h.x = f2bf(x); lo.x = f2bf(x - bf2f(h.x));
  x = v.y; h.y = f2bf(x); lo.y = f2bf(x - bf2f(h.y));
  x = v.z; h.z = f2bf(x); lo.z = f2bf(x - bf2f(h.z));
  x = v.w; h.w = f2bf(x); lo.w = f2bf(x - bf2f(h.w));
  *(ushort4*)&nH[base] = h;
  *(ushort4*)&nL[base] = lo;
}

// K9b: h3T[k][e] = h3[e][k], zero-padded to H3T_STRIDE edges (tiled transpose)
__global__ __launch_bounds__(256) void k_h3T(const float* __restrict__ y3,
                                             float* __restrict__ h3T) {
  __shared__ float tile[32][33];
  int bx = blockIdx.x;  // 1252 e-tiles
  int by = blockIdx.y;  // 4 k-tiles
  int tx = threadIdx.x & 31, ty = threadIdx.x >> 5;  // 32 x 8
#pragma unroll
  for (int i = 0; i < 4; ++i) {
    int e = bx * 32 + ty + 8 * i;
    float v = (e < 40000) ? y3[(size_t)e * 128 + by * 32 + tx] : 0.f;
    tile[ty + 8 * i][tx] = v;  // tile[e_local][k_local]
  }
  __syncthreads();
#pragma unroll
  for (int i = 0; i < 4; ++i) {
    int kk = by * 32 + ty + 8 * i;
    h3T[(size_t)kk * H3T_STRIDE + bx * 32 + tx] = tile[tx][ty + 8 * i];
  }
}

// K9c: build B2 packed in MFMA (32x32x16 bf16) B-fragment order, split hi/lo.
//   logical B_k[d][f] = W4[k*16384 + d*128 + f] * a4[d*128+f]  (k<128)
//              B_128[d][f] = nb4[d*128+f]                       (bias tail)
//   layout: per (k, H=f-half): 16384 bf16 = [dstep 8][cgg 2][s 2][lane 64][j 8]
//   with d = dstep*16 + (lane>>5)*8 + j, f = H*64 + cgg*32 + (lane&31)
//   hi planes at even 512-ushort blocks, lo at odd (lo unused this round).
__global__ __launch_bounds__(256) void k_buildB2(
    const float* __restrict__ W4, const float* __restrict__ a4,
    const float* __restrict__ nb4, ushort* __restrict__ B2) {
  int tid = blockIdx.x * 256 + threadIdx.x;  // exact 2,113,536 (grid 8256)
  int k = tid >> 14;            // 0..128
  int rem = tid & 16383;
  int H = rem >> 13;
  int rem2 = rem & 8191;
  int j = rem2 & 7;
  int lane = (rem2 >> 3) & 63;
  int cgg = (rem2 >> 9) & 1;
  int dstep = rem2 >> 10;       // 0..7
  int d = dstep * 16 + (lane >> 5) * 8 + j;
  int f = H * 64 + cgg * 32 + (lane & 31);
  int df = d * 128 + f;
  float v;
  if (k < 128) v = W4[(size_t)k * 16384 + df] * a4[df];
  else v = nb4[df];
  ushort hi = f2bf(v);
  ushort lo = f2bf(v - bf2f(hi));
  size_t base = ((size_t)(k * 2 + H)) * 16384 +
                (size_t)((dstep * 2 + cgg) * 2) * 512 + lane * 8 + j;
  B2[base] = hi;
  B2[base + 512] = lo;
}

// ---------------------------------------------------------------------------
// K10: MFMA contraction, pure-bf16 (hi planes only): 8 MFMA / k-chunk.
// message = sum_k h3[:,k] * (Xh @ Bh_k) + Xh @ C4h.
// grid (313, 2, 2): x = 128-edge tile, y = f-half (64 cols), z = k-range
// split (z=0: chunks 0..64, z=1: 65..128) for grid-quantization (1252 blocks).
// 512 thr (8 waves): wave (rg=w>>1, cg=w&1) owns one 32x32 MFMA tile.
// 16KB hi-chunk double-buffered via global_load_lds (2-phase).
// Epilogue: atomic segment-sum into msum; cnt only from (y==0,z==0).
__global__ __launch_bounds__(512) void k_biggemm3(
    const ushort* __restrict__ nodeH, const ushort* __restrict__ B2,
    const float* __restrict__ h3T, const int* __restrict__ eidx,
    float* __restrict__ msum, float* __restrict__ cnt) {
  __shared__ ushort Bl[2][8192];   // 2 x 16KB hi-plane chunks
  __shared__ int sidx[128], didx[128];
  const int t = threadIdx.x;
  const int e0 = blockIdx.x * 128;
  const int H = blockIdx.y;
  const int KZ = blockIdx.z;
  const int K0 = KZ ? 65 : 0;
  const int KN = KZ ? 64 : 65;
  const int w = t >> 6;
  const int l = t & 63;
  const int rg = w >> 1;
  const int cg = w & 1;
  const int dg = l >> 5;  // 0/1

  if (t < 256) {
    int e = e0 + (t >> 1);
    int v = (e < 40000) ? eidx[(size_t)e * 2 + (t & 1)] : 0;
    if (t & 1) didx[t >> 1] = v; else sidx[t >> 1] = v;
  }
  // stage chunk K0 (hi blocks at even 512-ushort offsets): 2 x 16B / thread
  {
    const size_t cb = (size_t)(K0 * 2 + H) * 16384;
#pragma unroll
    for (int j = 0; j < 2; ++j) {
      int flat = t + j * 512;  // 0..1023; bidx = flat>>6 in [0,16)
      gl_lds16(B2 + cb + (size_t)(flat >> 6) * 1024 + (flat & 63) * 8,
               &Bl[0][flat * 8]);
    }
  }
  __syncthreads();  // sidx ready; stage drained by barrier's vmcnt

  // per-lane X fragments (row = rg*32 + (l&31), d = d2*16 + dg*8 + j)
  const int myrow = rg * 32 + (l & 31);
  const int esrc = sidx[myrow];
  bf16x8 xh[8];
  {
    const ushort* ph = nodeH + (size_t)esrc * 128 + dg * 8;
#pragma unroll
    for (int d2 = 0; d2 < 8; ++d2) xh[d2] = *(const bf16x8*)(ph + d2 * 16);
  }

  f32x16 msg;
#pragma unroll
  for (int r = 0; r < 16; ++r) msg[r] = 0.f;

  for (int ki = 0; ki < KN; ++ki) {
    const int kc = K0 + ki;
    const int buf = ki & 1;
    // prefetch next hi-chunk into other buffer
    if (ki + 1 < KN) {
      const size_t cb = (size_t)((kc + 1) * 2 + H) * 16384;
#pragma unroll
      for (int j = 0; j < 2; ++j) {
        int flat = t + j * 512;
        gl_lds16(B2 + cb + (size_t)(flat >> 6) * 1024 + (flat & 63) * 8,
                 &Bl[buf ^ 1][flat * 8]);
      }
    }
    // h weights (broadcast per half-wave; kc==128 is the bias row, h == 1)
    float4 hv[4];
    if (kc < 128) {
      const float* hb = h3T + (size_t)kc * H3T_STRIDE + e0 + rg * 32 + 4 * dg;
#pragma unroll
      for (int q = 0; q < 4; ++q) hv[q] = *(const float4*)(hb + q * 8);
    } else {
#pragma unroll
      for (int q = 0; q < 4; ++q) hv[q] = make_float4(1.f, 1.f, 1.f, 1.f);
    }
    f32x16 u;
#pragma unroll
    for (int r = 0; r < 16; ++r) u[r] = 0.f;
    const ushort* bbase = &Bl[buf][0];
#pragma unroll
    for (int d2 = 0; d2 < 8; ++d2) {
      bf16x8 bh = *(const bf16x8*)(bbase + (d2 * 2 + cg) * 512 + l * 8);
      u = __builtin_amdgcn_mfma_f32_32x32x16_bf16(xh[d2], bh, u, 0, 0, 0);
    }
#pragma unroll
    for (int r = 0; r < 16; ++r) {
      float hval = ((const float*)&hv[r >> 2])[r & 3];
      msg[r] = fmaf(hval, u[r], msg[r]);
    }
    __syncthreads();  // waves done reading Bl[buf]; own prefetch drained
  }

  // epilogue: C layout row=(r&3)+8*(r>>2)+4*dg, col=l&31 (m74/m101 verified)
  const int fbase = H * 64 + cg * 32 + (l & 31);
#pragma unroll
  for (int r = 0; r < 16; ++r) {
    int lrow = rg * 32 + (r & 3) + 8 * (r >> 2) + 4 * dg;
    int ge = e0 + lrow;
    if (ge < 40000)
      atomicAdd(&msum[(size_t)didx[lrow] * 128 + fbase], msg[r]);
  }
  if (KZ == 0 && H == 0 && t < 128) {  // cnt exactly once per edge
    int ge = e0 + t;
    if (ge < 40000) atomicAdd(&cnt[didx[t]], 1.0f);
  }
}

// ---------------------------------------------------------------------------
// K11: msg = relu(msum/max(cnt,1) + bias)
__global__ __launch_bounds__(256) void k_msg(
    const float* __restrict__ msum, const float* __restrict__ cnt,
    const float* __restrict__ bias, float* __restrict__ msg) {
  int i = blockIdx.x * 256 + threadIdx.x;  // exact 2,560,000
  int nn = i >> 7, f = i & 127;
  float m = msum[i] / fmaxf(cnt[nn], 1.0f);
  msg[i] = fmaxf(m + bias[f], 0.f);
}

// K12: GRU gates -> h1, written twice (tuple output h1, h1[None])
__global__ __launch_bounds__(256) void k_gru(
    const float* __restrict__ gi, const float* __restrict__ gh,
    const float* __restrict__ h0, float* __restrict__ out) {
  int i = blockIdx.x * 256 + threadIdx.x;  // exact 2,560,000
  int nn = i >> 7, f = i & 127;
  size_t base = (size_t)nn * 384;
  float ir = gi[base + f], hr = gh[base + f];
  float iz = gi[base + 128 + f], hz = gh[base + 128 + f];
  float in_ = gi[base + 256 + f], hn = gh[base + 256 + f];
  float r = 1.f / (1.f + expf(-(ir + hr)));
  float z = 1.f / (1.f + expf(-(iz + hz)));
  float n = tanhf(in_ + r * hn);
  float h1 = (1.f - z) * n + z * h0[i];
  out[i] = h1;
  out[2560000 + i] = h1;
}

// ---------------------------------------------------------------------------
extern "C" void kernel_launch(void* const* d_in, const int* in_sizes, int n_in,
                              void* d_out, int out_size, void* d_ws,
                              size_t ws_size, hipStream_t stream) {
  (void)in_sizes; (void)n_in; (void)out_size; (void)ws_size;
  const float* node = (const float*)d_in[0];
  const int* eidx = (const int*)d_in[1];
  const float* edge = (const float*)d_in[2];
  const float* hidden = (const float*)d_in[3];
  const float* W1 = (const float*)d_in[4];
  const float* g1 = (const float*)d_in[5];
  const float* be1 = (const float*)d_in[6];
  const float* W2 = (const float*)d_in[7];
  const float* g2 = (const float*)d_in[8];
  const float* be2 = (const float*)d_in[9];
  const float* W3 = (const float*)d_in[10];
  const float* g3 = (const float*)d_in[11];
  const float* be3 = (const float*)d_in[12];
  const float* W4 = (const float*)d_in[13];
  const float* g4 = (const float*)d_in[14];
  const float* be4 = (const float*)d_in[15];
  const float* bias = (const float*)d_in[16];
  const float* Wih = (const float*)d_in[17];
  const float* Whh = (const float*)d_in[18];
  const float* bih = (const float*)d_in[19];
  const float* bhh = (const float*)d_in[20];
  float* out = (float*)d_out;

  // f64 stats region at ws start (12288 bytes), then f32 region.
  double* d64 = (double*)d_ws;
  double* sum1 = d64 + 0;
  double* sq1 = d64 + 256;
  double* sum2 = d64 + 512;
  double* sq2 = d64 + 768;
  double* sum3 = d64 + 1024;
  double* sq3 = d64 + 1152;
  double* hbarD = d64 + 1280;
  float* F = (float*)(d64 + 1536);

  size_t o = 0;
  float* y1 = F + o;   o += 10240000;  // 40000x256
  float* y2 = F + o;   o += 10240000;  // 40000x256
  float* y3 = F + o;   o += 5120000;   // 40000x128 (becomes h3)
  float* B2f = F + o;  o += 2113536;   // 129*2*16384 bf16
  float* msum = F + o; o += 2560000;
  float* cnt = F + o;  o += 20000;
  float* msg = F + o;  o += 2560000;
  float* WihT = F + o; o += 49152;
  float* WhhT = F + o; o += 49152;
  float* Cov = F + o;  o += 16384;
  float* a4 = F + o;   o += 16384;
  float* nb4 = F + o;  o += 16384;
  float* a1 = F + o;   o += 256;
  float* b1 = F + o;   o += 256;
  float* a2 = F + o;   o += 256;
  float* b2 = F + o;   o += 256;
  float* a3 = F + o;   o += 128;
  float* b3 = F + o;   o += 128;
  float* hbarF = F + o; o += 128;
  // Temporal overlays (order-dependent; producers AND consumers checked):
  //  Spart  = y1[0:2.62M)      written K6 (after y1's last read by k_gemm L2),
  //                            dead after K7b
  //  U      = y1[2.62M:4.72M)  written K8a, dead after K8b
  //  gi     = y1[2.56M:10.24M) written after biggemm3 (Spart/U dead)
  //  h3T    = y2[0:5.13M)      written K9b (after y2's last read by k_gemm L3),
  //                            dead after biggemm3
  //  hbarP  = y2[7.68M:7.70M)  disjoint from h3T
  //  gh     = y2[0:7.68M)      written after biggemm3 (h3T dead)
  //  nodeHL = msg slot: written by k_split_node FIRST; no producer touches
  //           msg until k_msg (after biggemm3, nodeHL dead).
  float* Spart = y1;
  float* U = y1 + 2621440;
  float* gi = y1 + 2560000;
  float* h3T = y2;                            // 128 x 40064
  float* gh = y2;
  float* hbarP = y2 + 7680000;
  ushort* nodeH = (ushort*)msg;               // 2,560,000 ushorts
  ushort* nodeL = ((ushort*)msg) + 2560000;   // 2,560,000 ushorts
  ushort* B2 = (ushort*)B2f;

  hipMemsetAsync(d_ws, 0, 12288, stream);
  hipMemsetAsync(msum, 0, (2560000 + 20000) * sizeof(float), stream);

  k_transpose_gru<<<384, 256, 0, stream>>>(Wih, Whh, WihT, WhhT);
  k_split_node<<<2500, 256, 0, stream>>>(node, nodeH, nodeL);

  // Edge MLP layers 1-3 with one-pass f64 BN stats
  k_edge_w1<<<2500, 256, 0, stream>>>(edge, W1, y1);
  k_colstats<<<256, 256, 0, stream>>>(y1, 40000, 256, sum1, sq1);
  k_finalize<<<1, 256, 0, stream>>>(sum1, sq1, g1, be1, a1, b1, 256, 1.0 / 40000.0);
  k_gemm<1><<<dim3(625, 2), 256, 0, stream>>>(y1, W2, y2, 40000, 256, 256, a1, b1, nullptr);
  k_colstats<<<256, 256, 0, stream>>>(y2, 40000, 256, sum2, sq2);
  k_finalize<<<1, 256, 0, stream>>>(sum2, sq2, g2, be2, a2, b2, 256, 1.0 / 40000.0);
  k_gemm<1><<<dim3(625, 1), 256, 0, stream>>>(y2, W3, y3, 40000, 256, 128, a2, b2, nullptr);
  k_colstats<<<256, 256, 0, stream>>>(y3, 40000, 128, sum3, sq3);
  k_finalize<<<1, 256, 0, stream>>>(sum3, sq3, g3, be3, a3, b3, 128, 1.0 / 40000.0);
  k_bnrelu_inplace<<<20000, 256, 0, stream>>>(y3, a3, b3, 5120000, 128);
  // y3 now holds h3

  // h3T (y2's MLP contents are dead now)
  k_h3T<<<dim3(1252, 4), 256, 0, stream>>>(y3, h3T);

  // Layer-4 BN stats analytically: mu4 = hbar@W4, var4 = w^T Cov w
  k_cov_partials<<<NSB, 256, 0, stream>>>(y3, Spart, hbarP);
  k_hbar<<<1, 128, 0, stream>>>(hbarP, hbarD, hbarF);
  k_cov<<<64, 256, 0, stream>>>(Spart, hbarD, Cov);
  k_covW4<<<128, 256, 0, stream>>>(Cov, W4, U);
  k_a4nb4<<<64, 256, 0, stream>>>(W4, U, hbarF, g4, be4, a4, nb4);
  k_buildB2<<<8256, 256, 0, stream>>>(W4, a4, nb4, B2);

  // MFMA contraction + segment-sum scatter (pure bf16, k-split grid)
  k_biggemm3<<<dim3(313, 2, 2), 512, 0, stream>>>(nodeH, B2, h3T, eidx,
                                                  msum, cnt);

  // Segment mean + bias + relu, then GRU
  k_msg<<<10000, 256, 0, stream>>>(msum, cnt, bias, msg);
  k_gemm<0><<<dim3(313, 3), 256, 0, stream>>>(msg, WihT, gi, 20000, 128, 384, nullptr, nullptr, bih);
  k_gemm<0><<<dim3(313, 3), 256, 0, stream>>>(hidden, WhhT, gh, 20000, 128, 384, nullptr, nullptr, bhh);
  k_gru<<<10000, 256, 0, stream>>>(gi, gh, hidden, out);
}

// Round 8
// 844.204 us; speedup vs baseline: 4.0944x; 1.0374x over previous
//
#include <hip/hip_runtime.h>
#include <cstdint>
#include <cstddef>

// Problem constants
#define N_NODE_C 20000
#define N_EDGE_C 40000
#define BN_EPS_F 1e-5f
#define NSB 160            // cov partial blocks (40000/160 = 250 rows each)
#define H3T_STRIDE 40064   // padded edge stride for h3T (313*128)

typedef __attribute__((ext_vector_type(8))) short bf16x8;
typedef __attribute__((ext_vector_type(16))) float f32x16;

// bf16 split helpers (RNE)
__device__ __forceinline__ ushort f2bf(float x) {
  unsigned u = __float_as_uint(x);
  unsigned r = u + 0x7fffu + ((u >> 16) & 1u);
  return (ushort)(r >> 16);
}
__device__ __forceinline__ float bf2f(ushort b) {
  return __uint_as_float(((unsigned)b) << 16);
}

__device__ __forceinline__ void gl_lds16(const ushort* g, ushort* l) {
  __builtin_amdgcn_global_load_lds(
      (const __attribute__((address_space(1))) unsigned int*)(g),
      (__attribute__((address_space(3))) unsigned int*)(l), 16, 0, 0);
}

// ---------------------------------------------------------------------------
// K1: y1 = edge(40000x16) @ W1(16x256)  (K=16: stays fp32 vector)
__global__ __launch_bounds__(256) void k_edge_w1(
    const float* __restrict__ edge, const float* __restrict__ W1,
    float* __restrict__ y1) {
  __shared__ float el[16][16];
  int e0 = blockIdx.x * 16;
  int t = threadIdx.x;
  el[t >> 4][t & 15] = edge[(size_t)e0 * 16 + t];
  __syncthreads();
  float w[16];
#pragma unroll
  for (int k = 0; k < 16; ++k) w[k] = W1[k * 256 + t];
#pragma unroll 4
  for (int e = 0; e < 16; ++e) {
    float acc = 0.f;
#pragma unroll
    for (int k = 0; k < 16; ++k) acc = fmaf(el[e][k], w[k], acc);
    y1[(size_t)(e0 + e) * 256 + t] = acc;
  }
}

// ---------------------------------------------------------------------------
// K2: per-column sum / sumsq (f64 atomics) of y[E x J], J in {128,256}
__global__ __launch_bounds__(256) void k_colstats(
    const float* __restrict__ y, int E, int J,
    double* __restrict__ sum, double* __restrict__ sumsq) {
  int t = threadIdx.x;
  int rpi = 256 / J;
  int col = t & (J - 1);
  int rof = t / J;
  double s = 0.0, q = 0.0;
  for (int r = blockIdx.x * rpi + rof; r < E; r += gridDim.x * rpi) {
    float v = y[(size_t)r * J + col];
    s += v;
    q += (double)v * (double)v;
  }
  atomicAdd(&sum[col], s);
  atomicAdd(&sumsq[col], q);
}

// K3: finalize BN affine per column: a = g*rsqrt(var+eps), b = be - mu*a
__global__ void k_finalize(const double* __restrict__ sum,
                           const double* __restrict__ sumsq,
                           const float* __restrict__ g,
                           const float* __restrict__ be,
                           float* __restrict__ a, float* __restrict__ b,
                           int J, double invE) {
  int j = threadIdx.x;
  if (j < J) {
    double mu = sum[j] * invE;
    double var = sumsq[j] * invE - mu * mu;
    float rstd = (float)(1.0 / sqrt(var + 1e-5));
    float aa = g[j] * rstd;
    a[j] = aa;
    b[j] = be[j] - (float)mu * aa;
  }
}

// ---------------------------------------------------------------------------
// K5: in-place h = relu(a*y + b) per column (J=128)
__global__ __launch_bounds__(256) void k_bnrelu_inplace(
    float* __restrict__ y, const float* __restrict__ a,
    const float* __restrict__ b, int n, int J) {
  int i = blockIdx.x * 256 + threadIdx.x;
  if (i < n) {
    int c = i & (J - 1);
    y[i] = fmaxf(fmaf(y[i], a[c], b[c]), 0.f);
  }
}

// ---------------------------------------------------------------------------
// K6: per-block partials of h3^T h3 (128x128) and column sums (Cov trick)
__global__ __launch_bounds__(256) void k_cov_partials(
    const float* __restrict__ h3, float* __restrict__ Spart,
    float* __restrict__ hbarP) {
  __shared__ float hl[2][128];
  int b = blockIdx.x;
  int t = threadIdx.x;
  int tr = t >> 4, tc = t & 15;
  float acc[8][8];
#pragma unroll
  for (int i = 0; i < 8; ++i)
#pragma unroll
    for (int j = 0; j < 8; ++j) acc[i][j] = 0.f;
  float cs = 0.f;
  int r0 = b * 250;
  for (int rs = 0; rs < 250; rs += 2) {
    hl[t >> 7][t & 127] = h3[(size_t)(r0 + rs + (t >> 7)) * 128 + (t & 127)];
    __syncthreads();
#pragma unroll
    for (int rr = 0; rr < 2; ++rr) {
      float a0[8], b0[8];
#pragma unroll
      for (int i = 0; i < 8; ++i) a0[i] = hl[rr][tr * 8 + i];
#pragma unroll
      for (int j = 0; j < 8; ++j) b0[j] = hl[rr][tc * 8 + j];
#pragma unroll
      for (int i = 0; i < 8; ++i)
#pragma unroll
        for (int j = 0; j < 8; ++j)
          acc[i][j] = fmaf(a0[i], b0[j], acc[i][j]);
    }
    if (t < 128) cs += hl[0][t] + hl[1][t];
    __syncthreads();
  }
  float* sp = &Spart[(size_t)b * 16384];
#pragma unroll
  for (int i = 0; i < 8; ++i)
#pragma unroll
    for (int j = 0; j < 8; j += 4) {
      float4 o;
      o.x = acc[i][j]; o.y = acc[i][j + 1];
      o.z = acc[i][j + 2]; o.w = acc[i][j + 3];
      *(float4*)&sp[(tr * 8 + i) * 128 + tc * 8 + j] = o;
    }
  if (t < 128) hbarP[b * 128 + t] = cs;
}

// K7a: hbar = (sum of partial colsums)/E  (f64)
__global__ void k_hbar(const float* __restrict__ hbarP,
                       double* __restrict__ hbarD, float* __restrict__ hbarF) {
  int t = threadIdx.x;  // 128
  double s = 0.0;
  for (int b = 0; b < NSB; ++b) s += (double)hbarP[b * 128 + t];
  s *= (1.0 / 40000.0);
  hbarD[t] = s;
  hbarF[t] = (float)s;
}

// K7b: Cov[k,l] = S/E - hbar_k*hbar_l
__global__ __launch_bounds__(256) void k_cov(
    const float* __restrict__ Spart, const double* __restrict__ hbarD,
    float* __restrict__ Cov) {
  int i = blockIdx.x * 256 + threadIdx.x;  // < 16384
  int k = i >> 7, l = i & 127;
  double s = 0.0;
  for (int b = 0; b < NSB; ++b) s += (double)Spart[(size_t)b * 16384 + i];
  Cov[i] = (float)(s * (1.0 / 40000.0) - hbarD[k] * hbarD[l]);
}

// K8a: U = Cov @ W4  (128 x 16384)
__global__ __launch_bounds__(256) void k_covW4(
    const float* __restrict__ Cov, const float* __restrict__ W4,
    float* __restrict__ U) {
  __shared__ float cl[8][128];
  int bk = blockIdx.x & 15, bj = blockIdx.x >> 4;
  int k0 = bk * 8, j0 = bj * 2048;
  int t = threadIdx.x;
  {
    float4 v = *(const float4*)&Cov[(size_t)(k0 + (t >> 5)) * 128 + (t & 31) * 4];
    *(float4*)&cl[t >> 5][(t & 31) * 4] = v;
  }
  __syncthreads();
  for (int ji = 0; ji < 8; ++ji) {
    int j = j0 + ji * 256 + t;
    float acc[8];
#pragma unroll
    for (int i = 0; i < 8; ++i) acc[i] = 0.f;
#pragma unroll 4
    for (int l = 0; l < 128; ++l) {
      float w = W4[(size_t)l * 16384 + j];
#pragma unroll
      for (int i = 0; i < 8; ++i) acc[i] = fmaf(cl[i][l], w, acc[i]);
    }
#pragma unroll
    for (int i = 0; i < 8; ++i) U[(size_t)(k0 + i) * 16384 + j] = acc[i];
  }
}

// K8b: mu4/var4 -> a4, nb4
__global__ __launch_bounds__(256) void k_a4nb4(
    const float* __restrict__ W4, const float* __restrict__ U,
    const float* __restrict__ hbarF, const float* __restrict__ g4,
    const float* __restrict__ be4, float* __restrict__ a4,
    float* __restrict__ nb4) {
  __shared__ float hb[128];
  int t = threadIdx.x;
  if (t < 128) hb[t] = hbarF[t];
  __syncthreads();
  int j = blockIdx.x * 256 + t;
  float macc = 0.f, vacc = 0.f;
#pragma unroll 4
  for (int k = 0; k < 128; ++k) {
    float w = W4[(size_t)k * 16384 + j];
    macc = fmaf(hb[k], w, macc);
    vacc = fmaf(w, U[(size_t)k * 16384 + j], vacc);
  }
  float aa = g4[j] * (1.0f / sqrtf(vacc + BN_EPS_F));
  a4[j] = aa;
  nb4[j] = be4[j] - macc * aa;
}

// ---------------------------------------------------------------------------
// K9a: split node into bf16 hi/lo row-major (nodeH used by biggemm3)
__global__ __launch_bounds__(256) void k_split_node(
    const float* __restrict__ node, ushort* __restrict__ nH,
    ushort* __restrict__ nL) {
  int i = blockIdx.x * 256 + threadIdx.x;  // grid 2500
  int base = i * 4;
  float4 v = *(const float4*)&node[base];
  ushort4 h, lo;
  float x;
  x = v.x; h.x = f2bf(x); lo.x = f2bf(x - bf2f(h.x));
  x = v.y; h.y = f2bf(x); lo.y = f2bf(x - bf2f(h.y));
  x = v.z; h.z = f2bf(x); lo.z = f2bf(x - bf2f(h.z));
  x = v.w; h.w = f2bf(x); lo.w = f2bf(x - bf2f(h.w));
  *(ushort4*)&nH[base] = h;
  *(ushort4*)&nL[base] = lo;
}

// K9b: h3T[k][e] = h3[e][k], zero-padded to H3T_STRIDE (tiled transpose)
__global__ __launch_bounds__(256) void k_h3T(const float* __restrict__ y3,
                                             float* __restrict__ h3T) {
  __shared__ float tile[32][33];
  int bx = blockIdx.x;  // 1252 e-tiles
  int by = blockIdx.y;  // 4 k-tiles
  int tx = threadIdx.x & 31, ty = threadIdx.x >> 5;  // 32 x 8
#pragma unroll
  for (int i = 0; i < 4; ++i) {
    int e = bx * 32 + ty + 8 * i;
    float v = (e < 40000) ? y3[(size_t)e * 128 + by * 32 + tx] : 0.f;
    tile[ty + 8 * i][tx] = v;
  }
  __syncthreads();
#pragma unroll
  for (int i = 0; i < 4; ++i) {
    int kk = by * 32 + ty + 8 * i;
    h3T[(size_t)kk * H3T_STRIDE + bx * 32 + tx] = tile[tx][ty + 8 * i];
  }
}

// K9c: build B2 (hi-plane only) packed in MFMA B-fragment order.
//   layout: [k 0..128][H 0..1][8192] with inner = (dstep*2+cgg)*512 + lane*8 + j
//   d = dstep*16+(lane>>5)*8+j, f = H*64+cgg*32+(lane&31)
//   R6 bug: grid was 4128 (k<=64 only) and slot half-sized -> msum clobber.
//   One write/thread => need 129*2*8192 = 2,113,536 threads = grid 8256.
__global__ __launch_bounds__(256) void k_buildB2(
    const float* __restrict__ W4, const float* __restrict__ a4,
    const float* __restrict__ nb4, ushort* __restrict__ B2) {
  int tid = blockIdx.x * 256 + threadIdx.x;  // exact 2,113,536 (grid 8256)
  int k = tid >> 14;            // 0..128
  int rem = tid & 16383;
  int H = rem >> 13;
  int rem2 = rem & 8191;        // == (dstep*2+cgg)*512 + lane*8 + j
  int j = rem2 & 7;
  int lane = (rem2 >> 3) & 63;
  int cgg = (rem2 >> 9) & 1;
  int dstep = rem2 >> 10;
  int d = dstep * 16 + (lane >> 5) * 8 + j;
  int f = H * 64 + cgg * 32 + (lane & 31);
  int df = d * 128 + f;
  float v;
  if (k < 128) v = W4[(size_t)k * 16384 + df] * a4[df];
  else v = nb4[df];
  B2[(size_t)(k * 2 + H) * 8192 + rem2] = f2bf(v);
}

// ---------------------------------------------------------------------------
// K9d: fragment-pack weights, split hi/lo.
// out layout: [kt][nt][plane][512] ushorts; k=kt*16+(lane>>5)*8+j, n=nt*32+(lane&31)
// TRANSPOSED: logical B[k][n] = W[n*ldw + k], else W[k*ldw + n].
template <int TRANSPOSED>
__global__ __launch_bounds__(256) void k_packW(
    const float* __restrict__ W, int Nd32, int ldw, ushort* __restrict__ out) {
  int tid = blockIdx.x * 256 + threadIdx.x;  // K*N threads
  int within = tid & 511;
  int g = tid >> 9;                 // kt*Nd32 + nt
  int nt = g % Nd32, kt = g / Nd32;
  int lane = within >> 3, j = within & 7;
  int k = kt * 16 + (lane >> 5) * 8 + j;
  int n = nt * 32 + (lane & 31);
  float v = TRANSPOSED ? W[(size_t)n * ldw + k] : W[(size_t)k * ldw + n];
  ushort hi = f2bf(v);
  ushort lo = f2bf(v - bf2f(hi));
  out[((size_t)g * 2 + 0) * 512 + within] = hi;
  out[((size_t)g * 2 + 1) * 512 + within] = lo;
}

// K9e: fragment-pack A rows (optional BN-affine+relu), split hi/lo.
// out: [m32][kt][plane][512]; row=m32*32+(lane&31), k=kt*16+(lane>>5)*8+j.
// Rows >= M zero-padded.
template <int MODE>  // 0 plain, 1 affine+relu
__global__ __launch_bounds__(256) void k_splitA(
    const float* __restrict__ A, int M, int Kd16,
    const float* __restrict__ ta, const float* __restrict__ tb,
    ushort* __restrict__ out) {
  int tid = blockIdx.x * 256 + threadIdx.x;  // M32*Kd16*64 threads
  int lane = tid & 63;
  int g = tid >> 6;                // m32*Kd16 + kt
  int kt = g % Kd16, m32 = g / Kd16;
  int row = m32 * 32 + (lane & 31);
  int kbase = kt * 16 + (lane >> 5) * 8;
  float v[8];
  if (row < M) {
    const float* src = A + (size_t)row * (Kd16 * 16) + kbase;
    float4 v0 = ((const float4*)src)[0];
    float4 v1 = ((const float4*)src)[1];
    v[0] = v0.x; v[1] = v0.y; v[2] = v0.z; v[3] = v0.w;
    v[4] = v1.x; v[5] = v1.y; v[6] = v1.z; v[7] = v1.w;
  } else {
#pragma unroll
    for (int u = 0; u < 8; ++u) v[u] = 0.f;
  }
  ushort hi[8], lo[8];
#pragma unroll
  for (int u = 0; u < 8; ++u) {
    float x = v[u];
    if (MODE == 1) {
      int k = kbase + u;
      x = fmaxf(fmaf(x, ta[k], tb[k]), 0.f);
    }
    hi[u] = f2bf(x);
    lo[u] = f2bf(x - bf2f(hi[u]));
  }
  size_t obase = ((size_t)g * 2) * 512 + lane * 8;
  *(ushort4*)&out[obase] = make_ushort4(hi[0], hi[1], hi[2], hi[3]);
  *(ushort4*)&out[obase + 4] = make_ushort4(hi[4], hi[5], hi[6], hi[7]);
  *(ushort4*)&out[obase + 512] = make_ushort4(lo[0], lo[1], lo[2], lo[3]);
  *(ushort4*)&out[obase + 516] = make_ushort4(lo[4], lo[5], lo[6], lo[7]);
}

// ---------------------------------------------------------------------------
// K9f: MFMA GEMM, split-3 bf16 (fp32-accurate): C = A @ B (+bias).
// A pack [M32][KD16][2][512], B pack [KD16][Nd32][2][512] (fragment order).
// 512 thr / 8 waves: rg=w>>1 (4x32 rows), cg=w&1 (2x32 cols). Full B n-slice
// staged to LDS once (single barrier, no loop barriers).
template <int KD16, int HAS_BIAS>
__global__ __launch_bounds__(512) void k_mfgemm(
    const ushort* __restrict__ Apk, const ushort* __restrict__ Bpk,
    float* __restrict__ C, int M, int Nd32, const float* __restrict__ bias) {
  __shared__ ushort Bl[KD16 * 4 * 512];  // KD16*4 KB
  const int t = threadIdx.x;
  const int mb = blockIdx.x, nb = blockIdx.y;
  const int w = t >> 6, l = t & 63;
  const int rg = w >> 1, cg = w & 1, dg = l >> 5;
  // stage B slice: KD16*4 blocks of 1KB, linear in LDS
  constexpr int passes = (KD16 * 4 * 64) / 512;  // 16B-units / threads
#pragma unroll
  for (int p = 0; p < passes; ++p) {
    int flat = t + p * 512;
    int blk = flat >> 6;             // kt*4 + cgg*2 + plane
    int off = (flat & 63) * 8;
    int kt = blk >> 2, cgg = (blk >> 1) & 1, plane = blk & 1;
    size_t srcb = ((size_t)(kt * Nd32 + nb * 2 + cgg) * 2 + plane) * 512 + off;
    gl_lds16(Bpk + srcb, &Bl[blk * 512 + off]);
  }
  __syncthreads();
  f32x16 u;
#pragma unroll
  for (int r = 0; r < 16; ++r) u[r] = 0.f;
  const int m32base = mb * 4 + rg;
#pragma unroll
  for (int kt = 0; kt < KD16; ++kt) {
    const ushort* ap = Apk + ((size_t)(m32base * KD16 + kt) * 2) * 512 + l * 8;
    bf16x8 ah = *(const bf16x8*)ap;
    bf16x8 al = *(const bf16x8*)(ap + 512);
    const ushort* bp = &Bl[(kt * 4 + cg * 2) * 512 + l * 8];
    bf16x8 bh = *(const bf16x8*)bp;
    bf16x8 bl2 = *(const bf16x8*)(bp + 512);
    u = __builtin_amdgcn_mfma_f32_32x32x16_bf16(ah, bh, u, 0, 0, 0);
    u = __builtin_amdgcn_mfma_f32_32x32x16_bf16(ah, bl2, u, 0, 0, 0);
    u = __builtin_amdgcn_mfma_f32_32x32x16_bf16(al, bh, u, 0, 0, 0);
  }
  const int N = Nd32 * 32;
  const int col = nb * 64 + cg * 32 + (l & 31);
  const float bv = HAS_BIAS ? bias[col] : 0.f;
#pragma unroll
  for (int r = 0; r < 16; ++r) {
    int row = mb * 128 + rg * 32 + (r & 3) + 8 * (r >> 2) + 4 * dg;
    if (row < M) C[(size_t)row * N + col] = u[r] + bv;
  }
}

// ---------------------------------------------------------------------------
// K10: MFMA contraction (pure bf16 hi): message = sum_k h3[:,k]*(Xh@Bh_k)+Xh@C4h
// grid (313,2,2): x=128-edge tile, y=f-half, z=k-range split.
__global__ __launch_bounds__(512) void k_biggemm3(
    const ushort* __restrict__ nodeH, const ushort* __restrict__ B2,
    const float* __restrict__ h3T, const int* __restrict__ eidx,
    float* __restrict__ msum, float* __restrict__ cnt) {
  __shared__ ushort Bl[2][8192];   // 2 x 16KB hi chunks
  __shared__ int sidx[128], didx[128];
  const int t = threadIdx.x;
  const int e0 = blockIdx.x * 128;
  const int H = blockIdx.y;
  const int KZ = blockIdx.z;
  const int K0 = KZ ? 65 : 0;
  const int KN = KZ ? 64 : 65;
  const int w = t >> 6;
  const int l = t & 63;
  const int rg = w >> 1;
  const int cg = w & 1;
  const int dg = l >> 5;

  if (t < 256) {
    int e = e0 + (t >> 1);
    int v = (e < 40000) ? eidx[(size_t)e * 2 + (t & 1)] : 0;
    if (t & 1) didx[t >> 1] = v; else sidx[t >> 1] = v;
  }
  {
    const size_t cb = (size_t)(K0 * 2 + H) * 8192;
#pragma unroll
    for (int jj = 0; jj < 2; ++jj) {
      int flat = t + jj * 512;  // 0..1023 16B-units
      gl_lds16(B2 + cb + (size_t)flat * 8, &Bl[0][flat * 8]);
    }
  }
  __syncthreads();

  const int myrow = rg * 32 + (l & 31);
  const int esrc = sidx[myrow];
  bf16x8 xh[8];
  {
    const ushort* ph = nodeH + (size_t)esrc * 128 + dg * 8;
#pragma unroll
    for (int d2 = 0; d2 < 8; ++d2) xh[d2] = *(const bf16x8*)(ph + d2 * 16);
  }

  f32x16 msg;
#pragma unroll
  for (int r = 0; r < 16; ++r) msg[r] = 0.f;

  for (int ki = 0; ki < KN; ++ki) {
    const int kc = K0 + ki;
    const int buf = ki & 1;
    if (ki + 1 < KN) {
      const size_t cb = (size_t)((kc + 1) * 2 + H) * 8192;
#pragma unroll
      for (int jj = 0; jj < 2; ++jj) {
        int flat = t + jj * 512;
        gl_lds16(B2 + cb + (size_t)flat * 8, &Bl[buf ^ 1][flat * 8]);
      }
    }
    float4 hv[4];
    if (kc < 128) {
      const float* hb = h3T + (size_t)kc * H3T_STRIDE + e0 + rg * 32 + 4 * dg;
#pragma unroll
      for (int q = 0; q < 4; ++q) hv[q] = *(const float4*)(hb + q * 8);
    } else {
#pragma unroll
      for (int q = 0; q < 4; ++q) hv[q] = make_float4(1.f, 1.f, 1.f, 1.f);
    }
    f32x16 u;
#pragma unroll
    for (int r = 0; r < 16; ++r) u[r] = 0.f;
    const ushort* bbase = &Bl[buf][0];
#pragma unroll
    for (int d2 = 0; d2 < 8; ++d2) {
      bf16x8 bh = *(const bf16x8*)(bbase + (d2 * 2 + cg) * 512 + l * 8);
      u = __builtin_amdgcn_mfma_f32_32x32x16_bf16(xh[d2], bh, u, 0, 0, 0);
    }
#pragma unroll
    for (int r = 0; r < 16; ++r) {
      float hval = ((const float*)&hv[r >> 2])[r & 3];
      msg[r] = fmaf(hval, u[r], msg[r]);
    }
    __syncthreads();
  }

  const int fbase = H * 64 + cg * 32 + (l & 31);
#pragma unroll
  for (int r = 0; r < 16; ++r) {
    int lrow = rg * 32 + (r & 3) + 8 * (r >> 2) + 4 * dg;
    int ge = e0 + lrow;
    if (ge < 40000)
      atomicAdd(&msum[(size_t)didx[lrow] * 128 + fbase], msg[r]);
  }
  if (KZ == 0 && H == 0 && t < 128) {
    int ge = e0 + t;
    if (ge < 40000) atomicAdd(&cnt[didx[t]], 1.0f);
  }
}

// ---------------------------------------------------------------------------
// K11: msg = relu(msum/max(cnt,1) + bias)
__global__ __launch_bounds__(256) void k_msg(
    const float* __restrict__ msum, const float* __restrict__ cnt,
    const float* __restrict__ bias, float* __restrict__ msg) {
  int i = blockIdx.x * 256 + threadIdx.x;  // exact 2,560,000
  int nn = i >> 7, f = i & 127;
  float m = msum[i] / fmaxf(cnt[nn], 1.0f);
  msg[i] = fmaxf(m + bias[f], 0.f);
}

// K12: GRU gates -> h1, written twice (tuple output h1, h1[None])
__global__ __launch_bounds__(256) void k_gru(
    const float* __restrict__ gi, const float* __restrict__ gh,
    const float* __restrict__ h0, float* __restrict__ out) {
  int i = blockIdx.x * 256 + threadIdx.x;  // exact 2,560,000
  int nn = i >> 7, f = i & 127;
  size_t base = (size_t)nn * 384;
  float ir = gi[base + f], hr = gh[base + f];
  float iz = gi[base + 128 + f], hz = gh[base + 128 + f];
  float in_ = gi[base + 256 + f], hn = gh[base + 256 + f];
  float r = 1.f / (1.f + expf(-(ir + hr)));
  float z = 1.f / (1.f + expf(-(iz + hz)));
  float n = tanhf(in_ + r * hn);
  float h1 = (1.f - z) * n + z * h0[i];
  out[i] = h1;
  out[2560000 + i] = h1;
}

// ---------------------------------------------------------------------------
extern "C" void kernel_launch(void* const* d_in, const int* in_sizes, int n_in,
                              void* d_out, int out_size, void* d_ws,
                              size_t ws_size, hipStream_t stream) {
  (void)in_sizes; (void)n_in; (void)out_size; (void)ws_size;
  const float* node = (const float*)d_in[0];
  const int* eidx = (const int*)d_in[1];
  const float* edge = (const float*)d_in[2];
  const float* hidden = (const float*)d_in[3];
  const float* W1 = (const float*)d_in[4];
  const float* g1 = (const float*)d_in[5];
  const float* be1 = (const float*)d_in[6];
  const float* W2 = (const float*)d_in[7];
  const float* g2 = (const float*)d_in[8];
  const float* be2 = (const float*)d_in[9];
  const float* W3 = (const float*)d_in[10];
  const float* g3 = (const float*)d_in[11];
  const float* be3 = (const float*)d_in[12];
  const float* W4 = (const float*)d_in[13];
  const float* g4 = (const float*)d_in[14];
  const float* be4 = (const float*)d_in[15];
  const float* bias = (const float*)d_in[16];
  const float* Wih = (const float*)d_in[17];
  const float* Whh = (const float*)d_in[18];
  const float* bih = (const float*)d_in[19];
  const float* bhh = (const float*)d_in[20];
  float* out = (float*)d_out;

  // f64 stats region at ws start (12288 bytes), then f32 region.
  double* d64 = (double*)d_ws;
  double* sum1 = d64 + 0;
  double* sq1 = d64 + 256;
  double* sum2 = d64 + 512;
  double* sq2 = d64 + 768;
  double* sum3 = d64 + 1024;
  double* sq3 = d64 + 1152;
  double* hbarD = d64 + 1280;
  float* F = (float*)(d64 + 1536);

  size_t o = 0;
  float* S1 = F + o;    o += 10320000;
  float* S2 = F + o;    o += 10320000;
  float* S3 = F + o;    o += 5150000;
  float* B2f = F + o;   o += 1056768;   // 2,113,536 ushorts (hi-only B2)
  float* msum = F + o;  o += 2560000;
  float* cnt = F + o;   o += 20000;
  float* msgb = F + o;  o += 2560000;
  float* Wihpkf = F + o; o += 49152;    // 98,304 ushorts
  float* Whhpkf = F + o; o += 49152;
  float* W2pkf = F + o;  o += 65536;    // 131,072 ushorts
  float* W3pkf = F + o;  o += 32768;
  float* Cov = F + o;   o += 16384;
  float* a4 = F + o;    o += 16384;
  float* nb4 = F + o;   o += 16384;
  float* a1 = F + o;    o += 256;
  float* b1 = F + o;    o += 256;
  float* a2 = F + o;    o += 256;
  float* b2 = F + o;    o += 256;
  float* a3 = F + o;    o += 128;
  float* b3 = F + o;    o += 128;
  float* hbarF = F + o; o += 128;
  // Overlay timeline (producer->consumer audited):
  //  S1: y1fp32 (edge_w1) -> read stats1+splitA -> y2fp32 (mfgemm L2 output)
  //      -> read stats2+splitA -> h3T[0:5.13M) (k_h3T) + Spart@5.2M + hbarP@7.9M
  //      + U@7.95M -> after biggemm3: gh[0:7.68M)
  //  S2: A2pk (splitA of y1) -> A3pk (splitA of y2fp32) -> gi[0:7.68M)
  //  S3: y3fp32 -> h3 (bnrelu) -> read h3T+cov -> msgpk[0:2.57M) + hidpk after
  //  msgb: nodeH/nodeL (split_node, alive through biggemm3) -> msg (k_msg)
  ushort* nodeH = (ushort*)msgb;
  ushort* nodeL = ((ushort*)msgb) + 2560000;
  ushort* B2 = (ushort*)B2f;
  ushort* W2pk = (ushort*)W2pkf;
  ushort* W3pk = (ushort*)W3pkf;
  ushort* Wihpk = (ushort*)Wihpkf;
  ushort* Whhpk = (ushort*)Whhpkf;
  ushort* A2pk = (ushort*)S2;           // also reused for A3pk
  float* h3T = S1;
  float* Spart = S1 + 5200000;
  float* hbarP = S1 + 7900000;
  float* U = S1 + 7950000;
  float* gh = S1;
  float* gi = S2;
  ushort* msgpk = (ushort*)S3;          // 5024 g's x 1024 ushorts
  ushort* hidpk = ((ushort*)S3) + 2572288 * 2;

  hipMemsetAsync(d_ws, 0, 12288, stream);
  hipMemsetAsync(msum, 0, (2560000 + 20000) * sizeof(float), stream);

  k_split_node<<<2500, 256, 0, stream>>>(node, nodeH, nodeL);
  k_packW<0><<<256, 256, 0, stream>>>(W2, 8, 256, W2pk);
  k_packW<0><<<128, 256, 0, stream>>>(W3, 4, 128, W3pk);
  k_packW<1><<<192, 256, 0, stream>>>(Wih, 12, 128, Wihpk);
  k_packW<1><<<192, 256, 0, stream>>>(Whh, 12, 128, Whhpk);

  // Edge MLP: L1 fp32, then MFMA split-3 for L2/L3
  k_edge_w1<<<2500, 256, 0, stream>>>(edge, W1, S1);
  k_colstats<<<256, 256, 0, stream>>>(S1, 40000, 256, sum1, sq1);
  k_finalize<<<1, 256, 0, stream>>>(sum1, sq1, g1, be1, a1, b1, 256, 1.0 / 40000.0);
  k_splitA<1><<<5008, 256, 0, stream>>>(S1, 40000, 16, a1, b1, A2pk);
  k_mfgemm<16, 0><<<dim3(313, 4), 512, 0, stream>>>(A2pk, W2pk, S1, 40000, 8, nullptr);
  k_colstats<<<256, 256, 0, stream>>>(S1, 40000, 256, sum2, sq2);
  k_finalize<<<1, 256, 0, stream>>>(sum2, sq2, g2, be2, a2, b2, 256, 1.0 / 40000.0);
  k_splitA<1><<<5008, 256, 0, stream>>>(S1, 40000, 16, a2, b2, A2pk);
  k_mfgemm<16, 0><<<dim3(313, 2), 512, 0, stream>>>(A2pk, W3pk, S3, 40000, 4, nullptr);
  k_colstats<<<256, 256, 0, stream>>>(S3, 40000, 128, sum3, sq3);
  k_finalize<<<1, 256, 0, stream>>>(sum3, sq3, g3, be3, a3, b3, 128, 1.0 / 40000.0);
  k_bnrelu_inplace<<<20000, 256, 0, stream>>>(S3, a3, b3, 5120000, 128);
  // S3 now holds h3

  k_h3T<<<dim3(1252, 4), 256, 0, stream>>>(S3, h3T);

  // Layer-4 BN stats analytically: mu4 = hbar@W4, var4 = w^T Cov w
  k_cov_partials<<<NSB, 256, 0, stream>>>(S3, Spart, hbarP);
  k_hbar<<<1, 128, 0, stream>>>(hbarP, hbarD, hbarF);
  k_cov<<<64, 256, 0, stream>>>(Spart, hbarD, Cov);
  k_covW4<<<128, 256, 0, stream>>>(Cov, W4, U);
  k_a4nb4<<<64, 256, 0, stream>>>(W4, U, hbarF, g4, be4, a4, nb4);
  k_buildB2<<<8256, 256, 0, stream>>>(W4, a4, nb4, B2);

  // MFMA contraction + segment-sum scatter
  k_biggemm3<<<dim3(313, 2, 2), 512, 0, stream>>>(nodeH, B2, h3T, eidx,
                                                  msum, cnt);

  // Segment mean + bias + relu, then GRU via MFMA split-3
  k_msg<<<10000, 256, 0, stream>>>(msum, cnt, bias, msgb);
  k_splitA<0><<<1256, 256, 0, stream>>>(msgb, 20000, 8, nullptr, nullptr, msgpk);
  k_splitA<0><<<1256, 256, 0, stream>>>(hidden, 20000, 8, nullptr, nullptr, hidpk);
  k_mfgemm<8, 1><<<dim3(157, 6), 512, 0, stream>>>(msgpk, Wihpk, gi, 20000, 12, bih);
  k_mfgemm<8, 1><<<dim3(157, 6), 512, 0, stream>>>(hidpk, Whhpk, gh, 20000, 12, bhh);
  k_gru<<<10000, 256, 0, stream>>>(gi, gh, hidden, out);
}